// Round 3
// baseline (11298.795 us; speedup 1.0000x reference)
//
#include <hip/hip_runtime.h>
#include <hip/hip_bf16.h>

// Problem dims
#define BB   256
#define TIN  336
#define TOUT 96
#define FF   32
#define HH   256

#define NGS 16   // H/gate-column slices (gi)
#define NBG 16   // batch groups (gb)
#define RPG 16   // batch rows per group
#define TPB 512

#define K4_L0 72    // K=288 = [Wih(32) | Whh(256)] in float4 units
#define K4_L1 128   // K=512 = [Wih1(256) | Whh1(256)]

// ws layout (float elements)
#define SZ_W0E  (16*K4_L0*64*4)   // 294912
#define SZ_W1E  (16*K4_L1*64*4)   // 524288
#define SZ_W0D  SZ_W0E
#define SZ_W1D  SZ_W1E
#define SZ_H    (2*256*256)       // double-buffered [parity][256 rows][256 cols]
#define OFF_W0E 0
#define OFF_W1E (OFF_W0E + SZ_W0E)
#define OFF_W0D (OFF_W1E + SZ_W1E)
#define OFF_W1D (OFF_W0D + SZ_W0D)
#define OFF_H0G (OFF_W1D + SZ_W1D)
#define OFF_H1G (OFF_H0G + SZ_H)
#define OFF_CTR (OFF_H1G + SZ_H)
#define SZ_CTR  512
#define TOTAL_WS (OFF_CTR + SZ_CTR)   // 1,901,056 floats = 7.6 MB

__device__ __forceinline__ float sigf(float x) { return 1.f / (1.f + __expf(-x)); }
__device__ __forceinline__ float tanhfast(float x) { return 1.f - 2.f / (__expf(2.f * x) + 1.f); }

// ---- prep: build [gi][k4][j][4] weight slices (j = gate*16+jj), zero h + counters ----
__global__ void prep_kernel(const float* __restrict__ eWih0, const float* __restrict__ eWhh0,
                            const float* __restrict__ eWih1, const float* __restrict__ eWhh1,
                            const float* __restrict__ dWih0, const float* __restrict__ dWhh0,
                            const float* __restrict__ dWih1, const float* __restrict__ dWhh1,
                            float* __restrict__ ws)
{
    for (long e = (long)blockIdx.x * blockDim.x + threadIdx.x; e < (long)TOTAL_WS;
         e += (long)gridDim.x * blockDim.x) {
        float v = 0.f;
        if (e < OFF_W1E) {                     // enc L0: K=288 = [Wih0 | Whh0]
            long ee = e - OFF_W0E;
            int u = (int)(ee & 3), jq = (int)((ee >> 2) & 63);
            long rem = ee >> 8; int k4 = (int)(rem % K4_L0); int gi = (int)(rem / K4_L0);
            int k = k4 * 4 + u;
            int gj = (jq >> 4) * 256 + gi * 16 + (jq & 15);
            v = (k < 32) ? eWih0[gj * 32 + k] : eWhh0[gj * 256 + (k - 32)];
        } else if (e < OFF_W0D) {              // enc L1: K=512 = [Wih1 | Whh1]
            long ee = e - OFF_W1E;
            int u = (int)(ee & 3), jq = (int)((ee >> 2) & 63);
            long rem = ee >> 8; int k4 = (int)(rem % K4_L1); int gi = (int)(rem / K4_L1);
            int k = k4 * 4 + u;
            int gj = (jq >> 4) * 256 + gi * 16 + (jq & 15);
            v = (k < 256) ? eWih1[gj * 256 + k] : eWhh1[gj * 256 + (k - 256)];
        } else if (e < OFF_W1D) {              // dec L0: K=288 = [Wih0 | Whh0]
            long ee = e - OFF_W0D;
            int u = (int)(ee & 3), jq = (int)((ee >> 2) & 63);
            long rem = ee >> 8; int k4 = (int)(rem % K4_L0); int gi = (int)(rem / K4_L0);
            int k = k4 * 4 + u;
            int gj = (jq >> 4) * 256 + gi * 16 + (jq & 15);
            v = (k < 32) ? dWih0[gj * 32 + k] : dWhh0[gj * 256 + (k - 32)];
        } else if (e < OFF_H0G) {              // dec L1: K=512 = [Wih1 | Whh1]
            long ee = e - OFF_W1D;
            int u = (int)(ee & 3), jq = (int)((ee >> 2) & 63);
            long rem = ee >> 8; int k4 = (int)(rem % K4_L1); int gi = (int)(rem / K4_L1);
            int k = k4 * 4 + u;
            int gj = (jq >> 4) * 256 + gi * 16 + (jq & 15);
            v = (k < 256) ? dWih1[gj * 256 + k] : dWhh1[gj * 256 + (k - 256)];
        } else {
            v = 0.f;                           // h buffers + counters
        }
        ws[e] = v;
    }
}

// ---- persistent seq2seq kernel: 256 wgs = 16 batch-groups x 16 gate-slices ----
__global__ __launch_bounds__(TPB) void lstm_main(
    const float* __restrict__ x,
    const float* __restrict__ eb0, const float* __restrict__ eb1,
    const float* __restrict__ db0, const float* __restrict__ db1,
    const float* __restrict__ Wout, const float* __restrict__ bout,
    float* __restrict__ ws, float* __restrict__ out)
{
    const int gi = blockIdx.x >> 4;   // gate-column slice 0..15
    const int gb = blockIdx.x & 15;   // batch group 0..15

    float* h0g = ws + OFF_H0G;
    float* h1g = ws + OFF_H1G;
    unsigned* ctr = (unsigned*)(ws + OFF_CTR) + gb * 32;

    const float4* W0e4 = (const float4*)(ws + OFF_W0E) + (size_t)gi * K4_L0 * 64;
    const float4* W1e4 = (const float4*)(ws + OFF_W1E) + (size_t)gi * K4_L1 * 64;
    const float4* W0d4 = (const float4*)(ws + OFF_W0D) + (size_t)gi * K4_L0 * 64;
    const float4* W1d4 = (const float4*)(ws + OFF_W1D) + (size_t)gi * K4_L1 * 64;

    const int t  = threadIdx.x;
    const int wv = t >> 6;            // wave 0..7 -> K-chunk
    const int ln = t & 63;            // lane -> gate row j = (ln>>4)*256 + gi*16 + (ln&15)

    __shared__ float tile[RPG][548];          // operand staging: [h|y/x|h] layouts
    __shared__ float pbuf[8][RPG][64];        // per-wave partial sums
    __shared__ float gred[RPG][68];           // reduced gates
    __shared__ float cst[2][RPG][16];         // cell states (wg-private, persistent)
    __shared__ float sbE0[64], sbE1[64], sbD0[64], sbD1[64];

    if (t < 64) {
        int gj = (t >> 4) * 256 + gi * 16 + (t & 15);
        sbE0[t] = eb0[gj]; sbE1[t] = eb1[gj]; sbD0[t] = db0[gj]; sbD1[t] = db1[gj];
    }
    if (t < 256) { cst[0][t >> 4][t & 15] = 0.f; cst[1][t >> 4][t & 15] = 0.f; }
    __syncthreads();

    int posts = 0;
    auto gsync = [&]() {
        __syncthreads();                      // all prior atomic h-stores issued & done
        ++posts;
        if (t == 0) {
            __hip_atomic_fetch_add(ctr, 1u, __ATOMIC_RELEASE, __HIP_MEMORY_SCOPE_AGENT);
            const unsigned tgt = (unsigned)(NGS * posts);
            while (__hip_atomic_load(ctr, __ATOMIC_ACQUIRE, __HIP_MEMORY_SCOPE_AGENT) < tgt)
                __builtin_amdgcn_s_sleep(1);
        }
        __syncthreads();
    };

    // cross-wg h exchange: relaxed agent-scope atomics (coherent by construction)
    auto loadH = [&](const float* src, int colbase) {
        const float* base = src + (size_t)gb * RPG * 256;
        for (int i = t; i < RPG * 256; i += TPB) {
            int r = i >> 8, c = i & 255;
            tile[r][colbase + c] =
                __hip_atomic_load(base + r * 256 + c, __ATOMIC_RELAXED, __HIP_MEMORY_SCOPE_AGENT);
        }
    };
    auto loadX = [&](int s) {                 // x_t -> cols 256..287
        for (int i = t; i < RPG * 8; i += TPB) {
            int r = i >> 3, c4 = i & 7;
            float4 v = ((const float4*)(x + ((size_t)(gb * RPG + r) * TIN + s) * FF))[c4];
            *(float4*)&tile[r][256 + c4 * 4] = v;
        }
    };

    // K-split GEMM: wave wv handles K4-chunk, partials reduced via LDS; then cell update.
    auto gemmPhase = [&](const float4* Wslice, int K4tot, int colbase,
                         const float* bias, int layer, float* hdst) {
        float acc[16];
        #pragma unroll
        for (int r = 0; r < 16; ++r) acc[r] = 0.f;
        const int chunk = K4tot >> 3;
        const int k4beg = wv * chunk;
        const float4* Wp = Wslice + ln;
        for (int k4 = k4beg; k4 < k4beg + chunk; ++k4) {
            float4 w = Wp[(size_t)k4 * 64];
            #pragma unroll
            for (int r = 0; r < 16; ++r) {
                float4 u = *(const float4*)&tile[r][colbase + k4 * 4];
                acc[r] = fmaf(w.x, u.x, fmaf(w.y, u.y, fmaf(w.z, u.z, fmaf(w.w, u.w, acc[r]))));
            }
        }
        #pragma unroll
        for (int r = 0; r < 16; ++r) pbuf[wv][r][ln] = acc[r];
        __syncthreads();
        for (int p = t; p < RPG * 64; p += TPB) {
            int r = p >> 6, j = p & 63;
            float s = bias[j];
            #pragma unroll
            for (int w8 = 0; w8 < 8; ++w8) s += pbuf[w8][r][j];
            gred[r][j] = s;
        }
        __syncthreads();
        if (t < 256) {
            int r = t >> 4, cc = t & 15;
            float xi = gred[r][cc],      xf = gred[r][16 + cc];
            float xg = gred[r][32 + cc], xo = gred[r][48 + cc];
            float c  = cst[layer][r][cc];
            float cn = sigf(xf) * c + sigf(xi) * tanhfast(xg);
            cst[layer][r][cc] = cn;
            float hv = sigf(xo) * tanhfast(cn);
            __hip_atomic_store(&hdst[(size_t)(gb * RPG + r) * 256 + gi * 16 + cc], hv,
                               __ATOMIC_RELAXED, __HIP_MEMORY_SCOPE_AGENT);
        }
        __syncthreads();
    };

    // y[r][f] from h1 in tile cols 0..255; optional write into tile col 256+f and to out (fp32!)
    auto computeY = [&](bool writeTile, int outTd) {
        int r = t >> 5, f = t & 31;
        const float4* tr = (const float4*)&tile[r][0];
        const float4* wf = (const float4*)Wout + (size_t)f * 64;
        float a = bout[f];
        #pragma unroll 8
        for (int k4 = 0; k4 < 64; ++k4) {
            float4 u = tr[k4], w = wf[k4];
            a = fmaf(u.x, w.x, fmaf(u.y, w.y, fmaf(u.z, w.z, fmaf(u.w, w.w, a))));
        }
        if (writeTile) tile[r][256 + f] = a;
        if (outTd >= 0 && (f >> 1) == gi)
            out[((size_t)(gb * RPG + r) * TOUT + outTd) * FF + f] = a;
    };

    // ---------------- encoder: 1 gsync/step ----------------
    for (int s = 0; s < TIN; ++s) {
        const int rp = s & 1, wp = rp ^ 1;
        loadX(s);                                   // cols 256..287
        loadH(h0g + rp * (SZ_H / 2), 288);          // h0(s-1) -> cols 288..543
        __syncthreads();
        gemmPhase(W0e4, K4_L0, 256, sbE0, 0, h0g + wp * (SZ_H / 2));
        gsync();                                    // h0(s) visible (and h1(s-1) by release order)
        loadH(h0g + wp * (SZ_H / 2), 0);            // h0(s)   -> cols 0..255
        loadH(h1g + rp * (SZ_H / 2), 256);          // h1(s-1) -> cols 256..511
        __syncthreads();
        gemmPhase(W1e4, K4_L1, 0, sbE1, 1, h1g + wp * (SZ_H / 2));
    }

    // ---------------- decoder: 2 gsyncs/step ----------------
    for (int s = TIN; s < TIN + TOUT; ++s) {
        const int rp = s & 1, wp = rp ^ 1;
        const int td = s - TIN;
        gsync();                                    // h0(s-1), h1(s-1) visible
        loadH(h0g + rp * (SZ_H / 2), 288);          // h0(s-1) -> cols 288..543
        if (td == 0) {
            { int r = t >> 5, f = t & 31;           // y0 = x[:, -1, :] -> cols 256..287
              tile[r][256 + f] = x[((size_t)(gb * RPG + r) * TIN + (TIN - 1)) * FF + f]; }
            __syncthreads();
        } else {
            loadH(h1g + rp * (SZ_H / 2), 0);        // h1(s-1) -> cols 0..255
            __syncthreads();
            computeY(true, td - 1);                 // y(td-1) -> cols 256..287 (+ out)
            __syncthreads();
        }
        gemmPhase(W0d4, K4_L0, 256, sbD0, 0, h0g + wp * (SZ_H / 2));
        gsync();                                    // h0(s) visible
        loadH(h0g + wp * (SZ_H / 2), 0);            // h0(s)   -> cols 0..255
        loadH(h1g + rp * (SZ_H / 2), 256);          // h1(s-1) -> cols 256..511
        __syncthreads();
        gemmPhase(W1d4, K4_L1, 0, sbD1, 1, h1g + wp * (SZ_H / 2));
    }

    // epilogue: y(TOUT-1) from h1(last)
    gsync();
    loadH(h1g + (((TIN + TOUT - 1) & 1) ^ 1) * (SZ_H / 2), 0);
    __syncthreads();
    computeY(false, TOUT - 1);
}

extern "C" void kernel_launch(void* const* d_in, const int* in_sizes, int n_in,
                              void* d_out, int out_size, void* d_ws, size_t ws_size,
                              hipStream_t stream) {
    const float* x     = (const float*)d_in[0];
    const float* eWih0 = (const float*)d_in[1];
    const float* eWhh0 = (const float*)d_in[2];
    const float* eb0   = (const float*)d_in[3];
    const float* eWih1 = (const float*)d_in[4];
    const float* eWhh1 = (const float*)d_in[5];
    const float* eb1   = (const float*)d_in[6];
    const float* dWih0 = (const float*)d_in[7];
    const float* dWhh0 = (const float*)d_in[8];
    const float* db0   = (const float*)d_in[9];
    const float* dWih1 = (const float*)d_in[10];
    const float* dWhh1 = (const float*)d_in[11];
    const float* db1   = (const float*)d_in[12];
    const float* dWout = (const float*)d_in[13];
    const float* dbout = (const float*)d_in[14];
    float* ws = (float*)d_ws;
    float* out = (float*)d_out;

    prep_kernel<<<1024, 256, 0, stream>>>(eWih0, eWhh0, eWih1, eWhh1,
                                          dWih0, dWhh0, dWih1, dWhh1, ws);
    lstm_main<<<NGS * NBG, TPB, 0, stream>>>(x, eb0, eb1, db0, db1,
                                             dWout, dbout, ws, out);
}

// Round 4
// 6444.485 us; speedup vs baseline: 1.7533x; 1.7533x over previous
//
#include <hip/hip_runtime.h>
#include <hip/hip_bf16.h>

// Problem dims
#define BB   256
#define TIN  336
#define TOUT 96
#define FF   32
#define HH   256

#define NGS 16   // gate-column slices (gi)
#define NBG 16   // batch groups (gb)
#define RPG 16   // batch rows per group
#define TPB 512

#define KB0 9    // L0: K=288 = [Wih(32) | Whh(256)], 9 kblocks of 32
#define KB1 16   // L1: K=512 = [Wih1 | Whh1], 16 kblocks
#define ASTRIDE 520  // A-tile row stride in bf16 elems (1040B = 260 words ≡ 4 mod 32 banks)

// ws layout. Weights as bf16 (ushort), [gi][nt][kb][lane][8] per region.
#define U_E0   0
#define N_L0   (16*4*KB0*64*8)     // 294912 ushorts
#define U_E1   (U_E0 + N_L0)
#define N_L1   (16*4*KB1*64*8)     // 524288 ushorts
#define U_D0   (U_E1 + N_L1)       // 819200
#define U_D1   (U_D0 + N_L0)       // 1114112
#define U_END  (U_D1 + N_L1)       // 1638400 ushorts = 819200 floats
#define F_H0G  (U_END / 2)         // 819200 (float offset)
#define HBUF   65536               // one parity buffer: 256x256 floats
#define F_H1G  (F_H0G + 2*HBUF)    // 950272
#define F_CTR  (F_H1G + 2*HBUF)    // 1081344
#define F_ZEND (F_CTR + 512)

// per-wg LDS weight slice: L0 at 0 (4*KB0*512=18432 us), L1 at 18432 (32768 us)
#define WL_L0  0
#define WL_L1  18432
#define WL_TOT 51200

typedef __bf16 bf16x8 __attribute__((ext_vector_type(8)));
typedef float  f32x4  __attribute__((ext_vector_type(4)));

__device__ __forceinline__ float sigf(float x) { return 1.f / (1.f + __expf(-x)); }
__device__ __forceinline__ float tanhfast(float x) { return 1.f - 2.f / (__expf(2.f * x) + 1.f); }
__device__ __forceinline__ unsigned short f2bf(float f) {   // RNE bf16
    union { float f; unsigned u; } v; v.f = f;
    unsigned r = v.u + 0x7FFF + ((v.u >> 16) & 1);
    return (unsigned short)(r >> 16);
}

// ---- prep: pack bf16 MFMA-fragment-ordered weight slices; zero h + counters ----
__global__ void prep_kernel(const float* __restrict__ eWih0, const float* __restrict__ eWhh0,
                            const float* __restrict__ eWih1, const float* __restrict__ eWhh1,
                            const float* __restrict__ dWih0, const float* __restrict__ dWhh0,
                            const float* __restrict__ dWih1, const float* __restrict__ dWhh1,
                            float* __restrict__ wsf)
{
    unsigned short* wsu = (unsigned short*)wsf;
    for (long u = (long)blockIdx.x * blockDim.x + threadIdx.x; u < (long)U_END;
         u += (long)gridDim.x * blockDim.x) {
        const float *Wih, *Whh; int KB; long l;
        if (u < U_E1)      { l = u - U_E0; KB = KB0; Wih = eWih0; Whh = eWhh0; }
        else if (u < U_D0) { l = u - U_E1; KB = KB1; Wih = eWih1; Whh = eWhh1; }
        else if (u < U_D1) { l = u - U_D0; KB = KB0; Wih = dWih0; Whh = dWhh0; }
        else               { l = u - U_D1; KB = KB1; Wih = dWih1; Whh = dWhh1; }
        int j = (int)(l & 7), lane = (int)((l >> 3) & 63);
        long rem = l >> 9;
        int kb = (int)(rem % KB), q = (int)(rem / KB);
        int nt = q & 3, gi = q >> 2;
        int k  = kb * 32 + ((lane >> 4) << 3) + j;
        int gj = nt * 256 + gi * 16 + (lane & 15);
        float v;
        if (KB == KB0) v = (k < 32)  ? Wih[gj * 32 + k]  : Whh[gj * 256 + (k - 32)];
        else           v = (k < 256) ? Wih[gj * 256 + k] : Whh[gj * 256 + (k - 256)];
        wsu[u] = f2bf(v);
    }
    for (long z = (long)blockIdx.x * blockDim.x + threadIdx.x; z < (long)(F_ZEND - F_H0G);
         z += (long)gridDim.x * blockDim.x)
        wsf[F_H0G + z] = 0.f;
}

// ---- persistent seq2seq: 256 wgs = 16 batch-groups x 16 gate-slices, MFMA core ----
__global__ __launch_bounds__(TPB) void lstm_main(
    const float* __restrict__ x,
    const float* __restrict__ eb0, const float* __restrict__ eb1,
    const float* __restrict__ db0, const float* __restrict__ db1,
    const float* __restrict__ Wout, const float* __restrict__ bout,
    float* __restrict__ ws, float* __restrict__ out)
{
    const int gi = blockIdx.x >> 4;
    const int gb = blockIdx.x & 15;   // stride-16 blocks -> same XCD per group

    const unsigned short* wsu = (const unsigned short*)ws;
    float* h0g = ws + F_H0G;
    float* h1g = ws + F_H1G;
    unsigned* ctr = (unsigned*)(ws + F_CTR) + gb * 32;

    const int t  = threadIdx.x;
    const int wv = t >> 6;
    const int ln = t & 63;

    __shared__ __align__(16) unsigned short Wlds[WL_TOT];    // 100 KB
    __shared__ __align__(16) unsigned short Atile[16 * ASTRIDE]; // 16.25 KB
    __shared__ __align__(16) float Hstage[16 * 256];         // 16 KB (fp32 h1 for y)
    __shared__ float pbuf[2][16][64];
    __shared__ float gred[16][68];
    __shared__ float cst[2][16][16];
    __shared__ float sbE0[64], sbE1[64], sbD0[64], sbD1[64];

    if (t < 64) {
        int gj = (t >> 4) * 256 + gi * 16 + (t & 15);
        sbE0[t] = eb0[gj]; sbE1[t] = eb1[gj]; sbD0[t] = db0[gj]; sbD1[t] = db1[gj];
    }
    if (t < 256) { cst[0][t >> 4][t & 15] = 0.f; cst[1][t >> 4][t & 15] = 0.f; }

    int posts = 0;
    auto gsync = [&]() {
        __syncthreads();
        ++posts;
        if (t == 0) {
            __hip_atomic_fetch_add(ctr, 1u, __ATOMIC_RELEASE, __HIP_MEMORY_SCOPE_AGENT);
            const unsigned tgt = (unsigned)(NGS * posts);
            while (__hip_atomic_load(ctr, __ATOMIC_ACQUIRE, __HIP_MEMORY_SCOPE_AGENT) < tgt)
                __builtin_amdgcn_s_sleep(1);
        }
        __syncthreads();
    };

    auto loadW = [&](const unsigned short* s0, const unsigned short* s1) {
        for (int i = t; i < N_L0 / 16 / 8; i += TPB)        // 2304 x 16B
            ((uint4*)Wlds)[i] = ((const uint4*)s0)[i];
        for (int i = t; i < N_L1 / 16 / 8; i += TPB)        // 4096 x 16B
            ((uint4*)(Wlds + WL_L1))[i] = ((const uint4*)s1)[i];
    };

    auto stageH = [&](const float* src, int colbase) {      // global fp32 h -> Atile bf16
        const float* base = src + (size_t)gb * RPG * 256;
        for (int i = t; i < 16 * 256; i += TPB) {
            int r = i >> 8, c = i & 255;
            float v = __hip_atomic_load(base + r * 256 + c, __ATOMIC_RELAXED,
                                        __HIP_MEMORY_SCOPE_AGENT);
            Atile[r * ASTRIDE + colbase + c] = f2bf(v);
        }
    };
    auto stageHtoStage = [&](const float* src) {            // global fp32 h -> Hstage fp32
        const float* base = src + (size_t)gb * RPG * 256;
        for (int i = t; i < 16 * 256; i += TPB)
            Hstage[i] = __hip_atomic_load(base + (i >> 8) * 256 + (i & 255),
                                          __ATOMIC_RELAXED, __HIP_MEMORY_SCOPE_AGENT);
    };
    auto stageHfromStage = [&](int colbase) {               // Hstage -> Atile bf16
        for (int i = t; i < 16 * 256; i += TPB) {
            int r = i >> 8, c = i & 255;
            Atile[r * ASTRIDE + colbase + c] = f2bf(Hstage[i]);
        }
    };
    auto stageX = [&](int s, int colbase) {                 // x(:,s,:) -> Atile bf16
        for (int i = t; i < 16 * 32; i += TPB) {
            int r = i >> 5, c = i & 31;
            Atile[r * ASTRIDE + colbase + c] =
                f2bf(x[((size_t)(gb * RPG + r) * TIN + s) * FF + c]);
        }
    };

    // MFMA phase: 8 waves = 4 N-tiles x 2 K-halves; pbuf reduce; cell update; h store.
    auto mfmaPhase = [&](int wbase, int KB, const float* bias, int layer, float* hdst) {
        const int nt = wv & 3, w2 = wv >> 2;
        const int half = (KB + 1) >> 1;
        const int kb0 = w2 ? half : 0;
        const int kbN = w2 ? (KB - half) : half;
        const int arow = ln & 15, ak = (ln >> 4) << 3;
        f32x4 acc = {0.f, 0.f, 0.f, 0.f};
        const unsigned short* ap = Atile + arow * ASTRIDE + kb0 * 32 + ak;
        const unsigned short* bp = Wlds + wbase + ((size_t)(nt * KB + kb0) * 64 + ln) * 8;
        for (int i = 0; i < kbN; ++i) {
            bf16x8 a = *(const bf16x8*)(ap + i * 32);
            bf16x8 b = *(const bf16x8*)(bp + (size_t)i * 512);
            acc = __builtin_amdgcn_mfma_f32_16x16x32_bf16(a, b, acc, 0, 0, 0);
        }
        #pragma unroll
        for (int rg = 0; rg < 4; ++rg)     // D: col=lane&15, row=(lane>>4)*4+rg
            pbuf[w2][(ln >> 4) * 4 + rg][nt * 16 + arow] = acc[rg];
        __syncthreads();
        for (int p = t; p < 16 * 64; p += TPB) {
            int r = p >> 6, j = p & 63;
            gred[r][j] = bias[j] + pbuf[0][r][j] + pbuf[1][r][j];
        }
        __syncthreads();
        if (t < 256) {
            int r = t >> 4, cc = t & 15;
            float xi = gred[r][cc],      xf = gred[r][16 + cc];
            float xg = gred[r][32 + cc], xo = gred[r][48 + cc];
            float c  = cst[layer][r][cc];
            float cn = sigf(xf) * c + sigf(xi) * tanhfast(xg);
            cst[layer][r][cc] = cn;
            float hv = sigf(xo) * tanhfast(cn);
            __hip_atomic_store(&hdst[(size_t)(gb * RPG + r) * 256 + gi * 16 + cc], hv,
                               __ATOMIC_RELAXED, __HIP_MEMORY_SCOPE_AGENT);
        }
        __syncthreads();
    };

    auto computeY = [&](bool writeTile, int outTd) {        // fp32 y from Hstage
        int r = t >> 5, f = t & 31;
        const float4* hr = (const float4*)&Hstage[r * 256];
        const float4* wf = (const float4*)(Wout + (size_t)f * 256);
        float a = bout[f];
        #pragma unroll 8
        for (int k4 = 0; k4 < 64; ++k4) {
            float4 u = hr[k4], w = wf[k4];
            a = fmaf(u.x, w.x, fmaf(u.y, w.y, fmaf(u.z, w.z, fmaf(u.w, w.w, a))));
        }
        if (writeTile) Atile[r * ASTRIDE + f] = f2bf(a);
        if (outTd >= 0 && (f >> 1) == gi)
            out[((size_t)(gb * RPG + r) * TOUT + outTd) * FF + f] = a;
    };

    // encoder weights -> LDS
    loadW(wsu + U_E0 + (size_t)gi * (4 * KB0 * 512), wsu + U_E1 + (size_t)gi * (4 * KB1 * 512));

    // ---------------- encoder: 1 gsync/step ----------------
    for (int s = 0; s < TIN; ++s) {
        const int rp = s & 1, wp = rp ^ 1;
        stageX(s, 0);                          // x_t -> cols 0..31
        stageH(h0g + rp * HBUF, 32);           // h0(s-1) -> cols 32..287
        __syncthreads();
        mfmaPhase(WL_L0, KB0, sbE0, 0, h0g + wp * HBUF);
        gsync();                               // h0(s) visible (h1(s-1) by release order)
        stageH(h0g + wp * HBUF, 0);            // h0(s)   -> cols 0..255
        stageH(h1g + rp * HBUF, 256);          // h1(s-1) -> cols 256..511
        __syncthreads();
        mfmaPhase(WL_L1, KB1, sbE1, 1, h1g + wp * HBUF);
    }

    // decoder weights -> LDS (enc phase done; first use is after gsync+syncthreads)
    loadW(wsu + U_D0 + (size_t)gi * (4 * KB0 * 512), wsu + U_D1 + (size_t)gi * (4 * KB1 * 512));

    // ---------------- decoder: 2 gsyncs/step ----------------
    for (int s = TIN; s < TIN + TOUT; ++s) {
        const int rp = s & 1, wp = rp ^ 1;
        const int td = s - TIN;
        gsync();                               // h0(s-1), h1(s-1) visible
        stageHtoStage(h1g + rp * HBUF);        // h1(s-1) -> Hstage fp32
        stageH(h0g + rp * HBUF, 32);           // h0(s-1) -> cols 32..287
        if (td == 0) {
            stageX(TIN - 1, 0);                // y0 = x[:, -1, :] -> cols 0..31
            __syncthreads();
        } else {
            __syncthreads();                   // Hstage ready
            computeY(true, td - 1);            // y(td-1) -> cols 0..31 + out
            __syncthreads();
        }
        mfmaPhase(WL_L0, KB0, sbD0, 0, h0g + wp * HBUF);
        gsync();                               // h0(s) visible
        stageH(h0g + wp * HBUF, 0);            // h0(s)   -> cols 0..255
        stageHfromStage(256);                  // h1(s-1) -> cols 256..511
        __syncthreads();
        mfmaPhase(WL_L1, KB1, sbD1, 1, h1g + wp * HBUF);
    }

    // epilogue: y(TOUT-1) from h1(last)
    gsync();
    stageHtoStage(h1g + (((TIN + TOUT - 1) & 1) ^ 1) * HBUF);
    __syncthreads();
    computeY(false, TOUT - 1);
}

extern "C" void kernel_launch(void* const* d_in, const int* in_sizes, int n_in,
                              void* d_out, int out_size, void* d_ws, size_t ws_size,
                              hipStream_t stream) {
    const float* x     = (const float*)d_in[0];
    const float* eWih0 = (const float*)d_in[1];
    const float* eWhh0 = (const float*)d_in[2];
    const float* eb0   = (const float*)d_in[3];
    const float* eWih1 = (const float*)d_in[4];
    const float* eWhh1 = (const float*)d_in[5];
    const float* eb1   = (const float*)d_in[6];
    const float* dWih0 = (const float*)d_in[7];
    const float* dWhh0 = (const float*)d_in[8];
    const float* db0   = (const float*)d_in[9];
    const float* dWih1 = (const float*)d_in[10];
    const float* dWhh1 = (const float*)d_in[11];
    const float* db1   = (const float*)d_in[12];
    const float* dWout = (const float*)d_in[13];
    const float* dbout = (const float*)d_in[14];
    float* ws = (float*)d_ws;
    float* out = (float*)d_out;

    prep_kernel<<<1024, 256, 0, stream>>>(eWih0, eWhh0, eWih1, eWhh1,
                                          dWih0, dWhh0, dWih1, dWhh1, ws);
    lstm_main<<<NGS * NBG, TPB, 0, stream>>>(x, eb0, eb1, db0, db1,
                                             dWout, dbout, ws, out);
}

// Round 5
// 5588.602 us; speedup vs baseline: 2.0218x; 1.1531x over previous
//
#include <hip/hip_runtime.h>
#include <hip/hip_bf16.h>

// Problem dims
#define BB   256
#define TIN  336
#define TOUT 96
#define FF   32
#define HH   256

#define NGS 16   // gate-column slices (gi)
#define NBG 16   // batch groups (gb)
#define RPG 16   // batch rows per group
#define TPB 512

#define KB0 9        // L0: K=288 = [Wih(32) | Whh(256)]
#define KB1 16       // L1: K=512 = [Wih1 | Whh1]
#define ASTRIDE 520  // A-tile row stride (bf16)
#define XSTRIDE 40   // X-tile row stride (bf16)

// ws layout in ushort units: bf16 weights [gi][nt][kb][lane][8], then bf16 h bufs, then ctr
#define N_L0  (16*4*KB0*64*8)      // 294912
#define N_L1  (16*4*KB1*64*8)      // 524288
#define U_E0  0
#define U_E1  (U_E0 + N_L0)
#define U_D0  (U_E1 + N_L1)
#define U_D1  (U_D0 + N_L0)
#define U_END (U_D1 + N_L1)        // 1638400
#define HPAR  65536                // one parity buffer: 256x256 bf16
#define U_H0  U_END
#define U_H1  (U_H0 + 2*HPAR)
#define U_CTR (U_H1 + 2*HPAR)      // even ushort index -> 4B aligned
#define U_ZEND (U_CTR + 1024)

// per-wg LDS weight slice
#define WL_L0  0
#define WL_L1  18432
#define WL_TOT 51200

typedef __bf16 bf16x8 __attribute__((ext_vector_type(8)));
typedef float  f32x4  __attribute__((ext_vector_type(4)));

__device__ __forceinline__ float sigf(float x) { return 1.f / (1.f + __expf(-x)); }
__device__ __forceinline__ float tanhfast(float x) { return 1.f - 2.f / (__expf(2.f * x) + 1.f); }
__device__ __forceinline__ unsigned short f2bf(float f) {   // RNE bf16
    union { float f; unsigned u; } v; v.f = f;
    unsigned r = v.u + 0x7FFF + ((v.u >> 16) & 1);
    return (unsigned short)(r >> 16);
}

// ---- prep: pack bf16 MFMA-fragment-ordered weight slices (layout proven in R3); zero h/ctr ----
__global__ void prep_kernel(const float* __restrict__ eWih0, const float* __restrict__ eWhh0,
                            const float* __restrict__ eWih1, const float* __restrict__ eWhh1,
                            const float* __restrict__ dWih0, const float* __restrict__ dWhh0,
                            const float* __restrict__ dWih1, const float* __restrict__ dWhh1,
                            float* __restrict__ wsf)
{
    unsigned short* wsu = (unsigned short*)wsf;
    for (long u = (long)blockIdx.x * blockDim.x + threadIdx.x; u < (long)U_END;
         u += (long)gridDim.x * blockDim.x) {
        const float *Wih, *Whh; int KB; long l;
        if (u < U_E1)      { l = u - U_E0; KB = KB0; Wih = eWih0; Whh = eWhh0; }
        else if (u < U_D0) { l = u - U_E1; KB = KB1; Wih = eWih1; Whh = eWhh1; }
        else if (u < U_D1) { l = u - U_D0; KB = KB0; Wih = dWih0; Whh = dWhh0; }
        else               { l = u - U_D1; KB = KB1; Wih = dWih1; Whh = dWhh1; }
        int j = (int)(l & 7), lane = (int)((l >> 3) & 63);
        long rem = l >> 9;
        int kb = (int)(rem % KB), q = (int)(rem / KB);
        int nt = q & 3, gi = q >> 2;
        int k  = kb * 32 + ((lane >> 4) << 3) + j;
        int gj = nt * 256 + gi * 16 + (lane & 15);
        float v;
        if (KB == KB0) v = (k < 32)  ? Wih[gj * 32 + k]  : Whh[gj * 256 + (k - 32)];
        else           v = (k < 256) ? Wih[gj * 256 + k] : Whh[gj * 256 + (k - 256)];
        wsu[u] = f2bf(v);
    }
    for (long z = (long)blockIdx.x * blockDim.x + threadIdx.x; z < (long)(U_ZEND - U_H0);
         z += (long)gridDim.x * blockDim.x)
        wsu[U_H0 + z] = 0;
}

// ---- persistent seq2seq: 256 wgs = 16 batch-groups x 16 gate-slices, MFMA core ----
__global__ __launch_bounds__(TPB) void lstm_main(
    const float* __restrict__ x,
    const float* __restrict__ eb0, const float* __restrict__ eb1,
    const float* __restrict__ db0, const float* __restrict__ db1,
    const float* __restrict__ Wout, const float* __restrict__ bout,
    float* __restrict__ ws, float* __restrict__ out)
{
    const int gi = blockIdx.x >> 4;
    const int gb = blockIdx.x & 15;   // stride-16 blocks -> same XCD per group

    unsigned short* wsu = (unsigned short*)ws;
    unsigned short* h0b = wsu + U_H0;
    unsigned short* h1b = wsu + U_H1;
    unsigned* ctr = (unsigned*)(wsu + U_CTR) + gb * 32;

    const int t  = threadIdx.x;
    const int wv = t >> 6;
    const int ln = t & 63;

    __shared__ __align__(16) unsigned short Wlds[WL_TOT];          // 100 KB
    __shared__ __align__(16) unsigned short Atile[16 * ASTRIDE];   // 16.25 KB (h operands)
    __shared__ __align__(16) unsigned short Xtile[16 * XSTRIDE];   // 1.25 KB (x or y)
    __shared__ float pbuf[2][16][68];
    __shared__ float cst[2][16][16];
    __shared__ float sb[4][64];

    if (t < 64) {
        int gj = (t >> 4) * 256 + gi * 16 + (t & 15);
        sb[0][t] = eb0[gj]; sb[1][t] = eb1[gj]; sb[2][t] = db0[gj]; sb[3][t] = db1[gj];
    }
    if (t < 256) { cst[0][t >> 4][t & 15] = 0.f; cst[1][t >> 4][t & 15] = 0.f; }

    int posts = 0;
    auto gsync = [&]() {
        __syncthreads();                      // all waves' h stores drained (vmcnt before barrier)
        ++posts;
        if (t == 0) {
            __hip_atomic_fetch_add(ctr, 1u, __ATOMIC_RELEASE, __HIP_MEMORY_SCOPE_AGENT);
            const unsigned tgt = (unsigned)(NGS * posts);
            while (__hip_atomic_load(ctr, __ATOMIC_ACQUIRE, __HIP_MEMORY_SCOPE_AGENT) < tgt)
                __builtin_amdgcn_s_sleep(1);  // acquire invalidates L1/L2 before our plain loads
        }
        __syncthreads();
    };

    auto loadW = [&](const unsigned short* s0, const unsigned short* s1) {
        for (int i = t; i < N_L0 / 16 / 8; i += TPB)
            ((uint4*)Wlds)[i] = ((const uint4*)s0)[i];
        for (int i = t; i < N_L1 / 16 / 8; i += TPB)
            ((uint4*)(Wlds + WL_L1))[i] = ((const uint4*)s1)[i];
    };

    // one uint4 (8 bf16) per thread: 16 rows x 256 cols bf16 in a single L2 round-trip
    auto stageHbf = [&](const unsigned short* src, int colbase) {
        const unsigned short* base = src + (size_t)gb * RPG * 256;
        int r = t >> 5, c8 = t & 31;
        uint4 v = *(const uint4*)(base + r * 256 + c8 * 8);
        *(uint4*)(Atile + r * ASTRIDE + colbase + c8 * 8) = v;
    };
    auto stageX = [&](int s) {
        int r = t >> 5, c = t & 31;
        Xtile[r * XSTRIDE + c] = f2bf(x[((size_t)(gb * RPG + r) * TIN + s) * FF + c]);
    };

    // MFMA phase: 8 waves = 4 N-tiles x 2 K-halves; pbuf reduce; fused cell update + bf16 h store
    auto phase = [&](int wbase, int KB, bool withX, const float* bias, int layer,
                     unsigned short* hdst) {
        const int nt = wv & 3, w2 = wv >> 2;
        const int arow = ln & 15, ak = (ln >> 4) << 3;
        const int kbs = w2 ? (KB / 2) : 0;
        const int kbe = w2 ? KB : (KB / 2);
        f32x4 acc = {0.f, 0.f, 0.f, 0.f};
        #pragma unroll
        for (int kb = kbs; kb < kbe; ++kb) {
            bf16x8 a;
            if (withX && kb == 0) a = *(const bf16x8*)(Xtile + arow * XSTRIDE + ak);
            else {
                int koff = withX ? (kb - 1) * 32 : kb * 32;
                a = *(const bf16x8*)(Atile + arow * ASTRIDE + koff + ak);
            }
            bf16x8 b = *(const bf16x8*)(Wlds + wbase + ((size_t)(nt * KB + kb) * 64 + ln) * 8);
            acc = __builtin_amdgcn_mfma_f32_16x16x32_bf16(a, b, acc, 0, 0, 0);
        }
        #pragma unroll
        for (int rg = 0; rg < 4; ++rg)        // D: col=lane&15, row=(lane>>4)*4+rg
            pbuf[w2][(ln >> 4) * 4 + rg][nt * 16 + arow] = acc[rg];
        __syncthreads();
        if (t < 256) {
            int r = t >> 4, cc = t & 15;
            float xi = bias[cc]      + pbuf[0][r][cc]      + pbuf[1][r][cc];
            float xf = bias[16 + cc] + pbuf[0][r][16 + cc] + pbuf[1][r][16 + cc];
            float xg = bias[32 + cc] + pbuf[0][r][32 + cc] + pbuf[1][r][32 + cc];
            float xo = bias[48 + cc] + pbuf[0][r][48 + cc] + pbuf[1][r][48 + cc];
            float c  = cst[layer][r][cc];
            float cn = sigf(xf) * c + sigf(xi) * tanhfast(xg);
            cst[layer][r][cc] = cn;
            float hv = sigf(xo) * tanhfast(cn);
            hdst[(size_t)(gb * RPG + r) * 256 + gi * 16 + cc] = f2bf(hv);
        }
        __syncthreads();
    };

    // y[r][f] from bf16 h1 in Atile cols 256..511, fp32 accumulate
    auto computeY = [&](int outTd, bool toX) {
        const int r = t >> 5, f = t & 31;
        const unsigned* hp = (const unsigned*)(Atile + (size_t)r * ASTRIDE + 256);
        const float* wf = Wout + (size_t)f * 256;
        float a = bout[f];
        #pragma unroll 8
        for (int q = 0; q < 128; ++q) {
            unsigned u = hp[q];
            float2 w = *(const float2*)(wf + q * 2);
            a = fmaf(__uint_as_float(u << 16), w.x, a);
            a = fmaf(__uint_as_float(u & 0xffff0000u), w.y, a);
        }
        if (toX) Xtile[r * XSTRIDE + f] = f2bf(a);
        if (outTd >= 0 && (f >> 1) == gi)
            out[((size_t)(gb * RPG + r) * TOUT + outTd) * FF + f] = a;
    };

    // ---- init: encoder weights -> LDS; A-tile h0(-1)=0; Xtile = x(0) ----
    loadW(wsu + U_E0 + (size_t)gi * (4 * KB0 * 512), wsu + U_E1 + (size_t)gi * (4 * KB1 * 512));
    { int r = t >> 5, c8 = t & 31; uint4 z = {0u,0u,0u,0u};
      *(uint4*)(Atile + r * ASTRIDE + c8 * 8) = z; }
    stageX(0);
    __syncthreads();

    // ---- encoder: 1 gsync/step ----
    for (int s = 0; s < TIN; ++s) {
        const int rp = s & 1, wp = rp ^ 1;
        phase(WL_L0, KB0, true, sb[0], 0, h0b + wp * HPAR);   // uses Xtile + cols0..255=h0(s-1)
        gsync();                                              // h0(s) (+h1(s-1) by release order)
        stageHbf(h0b + wp * HPAR, 0);                         // h0(s)   -> cols 0..255
        stageHbf(h1b + rp * HPAR, 256);                       // h1(s-1) -> cols 256..511
        if (s + 1 < TIN) stageX(s + 1);
        __syncthreads();
        phase(WL_L1, KB1, false, sb[1], 1, h1b + wp * HPAR);
    }

    // ---- decoder weights -> LDS (all waves past enc phases; barriers in gsync publish) ----
    loadW(wsu + U_D0 + (size_t)gi * (4 * KB0 * 512), wsu + U_D1 + (size_t)gi * (4 * KB1 * 512));

    // ---- decoder: 2 gsyncs/step ----
    for (int s = TIN; s < TIN + TOUT; ++s) {
        const int rp = s & 1, wp = rp ^ 1, td = s - TIN;
        gsync();                                              // h1(s-1) visible
        stageHbf(h1b + rp * HPAR, 256);                       // h1(s-1) -> cols 256..511
        __syncthreads();
        if (td == 0) { int r = t >> 5, c = t & 31;            // y0 = x[:, -1, :]
            Xtile[r * XSTRIDE + c] = f2bf(x[((size_t)(gb * RPG + r) * TIN + TIN - 1) * FF + c]); }
        else computeY(td - 1, true);                          // y(td-1) -> Xtile + out
        __syncthreads();
        phase(WL_L0, KB0, true, sb[2], 0, h0b + wp * HPAR);   // Xtile + cols0..255=h0(s-1)
        gsync();                                              // h0(s) visible
        stageHbf(h0b + wp * HPAR, 0);                         // h0(s) -> cols 0..255
        __syncthreads();
        phase(WL_L1, KB1, false, sb[3], 1, h1b + wp * HPAR);
    }

    // ---- epilogue: y(TOUT-1) from h1(431) (parity 0) ----
    gsync();
    stageHbf(h1b + 0 * HPAR, 256);
    __syncthreads();
    computeY(TOUT - 1, false);
}

extern "C" void kernel_launch(void* const* d_in, const int* in_sizes, int n_in,
                              void* d_out, int out_size, void* d_ws, size_t ws_size,
                              hipStream_t stream) {
    const float* x     = (const float*)d_in[0];
    const float* eWih0 = (const float*)d_in[1];
    const float* eWhh0 = (const float*)d_in[2];
    const float* eb0   = (const float*)d_in[3];
    const float* eWih1 = (const float*)d_in[4];
    const float* eWhh1 = (const float*)d_in[5];
    const float* eb1   = (const float*)d_in[6];
    const float* dWih0 = (const float*)d_in[7];
    const float* dWhh0 = (const float*)d_in[8];
    const float* db0   = (const float*)d_in[9];
    const float* dWih1 = (const float*)d_in[10];
    const float* dWhh1 = (const float*)d_in[11];
    const float* db1   = (const float*)d_in[12];
    const float* dWout = (const float*)d_in[13];
    const float* dbout = (const float*)d_in[14];
    float* ws = (float*)d_ws;
    float* out = (float*)d_out;

    prep_kernel<<<1024, 256, 0, stream>>>(eWih0, eWhh0, eWih1, eWhh1,
                                          dWih0, dWhh0, dWih1, dWhh1, ws);
    lstm_main<<<NGS * NBG, TPB, 0, stream>>>(x, eb0, eb1, db0, db1,
                                             dWout, dbout, ws, out);
}

// Round 6
// 3186.312 us; speedup vs baseline: 3.5460x; 1.7539x over previous
//
#include <hip/hip_runtime.h>
#include <hip/hip_bf16.h>

// Problem dims
#define BB   256
#define TIN  336
#define TOUT 96
#define FF   32
#define HH   256

#define NGS 16   // gate-column slices (gi)
#define NBG 16   // batch groups (gb)
#define RPG 16   // batch rows per group
#define TPB 512

#define KB0 9        // L0: K=288 = [x/y(32) | h(256)]
#define KB1 16       // L1: K=512 = [h0 | h1]
#define ASTRIDE 520  // A-tile row stride (bf16)
#define XSTRIDE 40   // X-tile row stride (bf16)

// ws layout in ushort units
#define N_L0  (16*4*KB0*64*8)      // 294912
#define N_L1  (16*4*KB1*64*8)      // 524288
#define U_E0  0
#define U_E1  (U_E0 + N_L0)
#define U_D0  (U_E1 + N_L1)
#define U_D1  (U_D0 + N_L0)
#define U_END (U_D1 + N_L1)        // 1638400
#define HPAR  65536                // one parity buffer: 256x256 bf16
#define U_H0  U_END
#define U_H1  (U_H0 + 2*HPAR)
#define U_CTR (U_H1 + 2*HPAR)      // flags: [gb][32 uints] = 128B/group
#define U_WOUT (U_CTR + 2048)      // Wout bf16, MFMA-B layout [nt(2)][kb(8)][lane][8]
#define U_ZEND (U_WOUT + 8192)

// per-wg LDS weight slice
#define WL_L0  0
#define WL_L1  18432
#define WL_TOT 51200

// gate pre-activation: bias + 2 K-half partials
#define GATE(bias, g, r, cc) (bias[(g)*16 + (cc)] + pbuf[0][r][(g)*16 + (cc)] + pbuf[1][r][(g)*16 + (cc)])

typedef __bf16 bf16x8 __attribute__((ext_vector_type(8)));
typedef float  f32x4  __attribute__((ext_vector_type(4)));

__device__ __forceinline__ float sigf(float x) { return 1.f / (1.f + __expf(-x)); }
__device__ __forceinline__ float tanhfast(float x) { return 1.f - 2.f / (__expf(2.f * x) + 1.f); }
__device__ __forceinline__ unsigned short f2bf(float f) {   // RNE bf16
    union { float f; unsigned u; } v; v.f = f;
    unsigned r = v.u + 0x7FFF + ((v.u >> 16) & 1);
    return (unsigned short)(r >> 16);
}

// ---- prep: pack bf16 MFMA-fragment weight slices + WoutB; zero h bufs + flags ----
__global__ void prep_kernel(const float* __restrict__ eWih0, const float* __restrict__ eWhh0,
                            const float* __restrict__ eWih1, const float* __restrict__ eWhh1,
                            const float* __restrict__ dWih0, const float* __restrict__ dWhh0,
                            const float* __restrict__ dWih1, const float* __restrict__ dWhh1,
                            const float* __restrict__ Wout,  float* __restrict__ wsf)
{
    unsigned short* wsu = (unsigned short*)wsf;
    for (long u = (long)blockIdx.x * blockDim.x + threadIdx.x; u < (long)U_END;
         u += (long)gridDim.x * blockDim.x) {
        const float *Wih, *Whh; int KB; long l;
        if (u < U_E1)      { l = u - U_E0; KB = KB0; Wih = eWih0; Whh = eWhh0; }
        else if (u < U_D0) { l = u - U_E1; KB = KB1; Wih = eWih1; Whh = eWhh1; }
        else if (u < U_D1) { l = u - U_D0; KB = KB0; Wih = dWih0; Whh = dWhh0; }
        else               { l = u - U_D1; KB = KB1; Wih = dWih1; Whh = dWhh1; }
        int j = (int)(l & 7), lane = (int)((l >> 3) & 63);
        long rem = l >> 9;
        int kb = (int)(rem % KB), q = (int)(rem / KB);
        int nt = q & 3, gi = q >> 2;
        int k  = kb * 32 + ((lane >> 4) << 3) + j;
        int gj = nt * 256 + gi * 16 + (lane & 15);
        float v;
        if (KB == KB0) v = (k < 32)  ? Wih[gj * 32 + k]  : Whh[gj * 256 + (k - 32)];
        else           v = (k < 256) ? Wih[gj * 256 + k] : Whh[gj * 256 + (k - 256)];
        wsu[u] = f2bf(v);
    }
    for (long z = (long)blockIdx.x * blockDim.x + threadIdx.x; z < (long)(U_WOUT - U_H0);
         z += (long)gridDim.x * blockDim.x)
        wsu[U_H0 + z] = 0;
    for (long w = (long)blockIdx.x * blockDim.x + threadIdx.x; w < 8192;
         w += (long)gridDim.x * blockDim.x) {
        int j = (int)(w & 7), lane = (int)((w >> 3) & 63);
        long rem = w >> 9;
        int kb = (int)(rem & 7), nt = (int)(rem >> 3);
        int n = nt * 16 + (lane & 15);
        int k = kb * 32 + ((lane >> 4) << 3) + j;
        wsu[U_WOUT + w] = f2bf(Wout[n * 256 + k]);
    }
}

// ---- persistent seq2seq: 256 wgs = 16 batch-groups x 16 gate-slices, MFMA core ----
__global__ __launch_bounds__(TPB) void lstm_main(
    const float* __restrict__ x,
    const float* __restrict__ eb0, const float* __restrict__ eb1,
    const float* __restrict__ db0, const float* __restrict__ db1,
    const float* __restrict__ Wout, const float* __restrict__ bout,
    float* __restrict__ ws, float* __restrict__ out)
{
    const int gi = blockIdx.x >> 4;
    const int gb = blockIdx.x & 15;   // stride-16 blocks -> same XCD per group (perf heuristic)

    unsigned short* wsu = (unsigned short*)ws;
    const unsigned short* h0u = wsu + U_H0;     // consumer view (plain uint4 loads post-fence)
    const unsigned short* h1u = wsu + U_H1;
    unsigned* h0d = (unsigned*)(wsu + U_H0);    // producer view (write-through atomic dwords)
    unsigned* h1d = (unsigned*)(wsu + U_H1);
    unsigned* flg = (unsigned*)(wsu + U_CTR) + gb * 32;

    const int t  = threadIdx.x;
    const int wv = t >> 6;
    const int ln = t & 63;

    __shared__ __align__(16) unsigned short Wlds[WL_TOT];          // 100 KB
    __shared__ __align__(16) unsigned short Atile[16 * ASTRIDE];   // 16.25 KB
    __shared__ __align__(16) unsigned short Xtile[16 * XSTRIDE];   // 1.25 KB
    __shared__ __align__(16) unsigned short WoutLds[8192];         // 16 KB
    __shared__ float pbuf[2][16][68];
    __shared__ float pbufY[4][16][32];
    __shared__ float cst[2][16][16];
    __shared__ float sb[4][64];
    __shared__ float sbout[32];

    if (t < 64) {
        int gj = (t >> 4) * 256 + gi * 16 + (t & 15);
        sb[0][t] = eb0[gj]; sb[1][t] = eb1[gj]; sb[2][t] = db0[gj]; sb[3][t] = db1[gj];
    }
    if (t < 256) { cst[0][t >> 4][t & 15] = 0.f; cst[1][t >> 4][t & 15] = 0.f; }

    int posts = 0;
    // Always preceded by a __syncthreads() => every wave's global stores are
    // vmcnt-drained before the release store below (visible via happens-before).
    auto gsync = [&]() {
        ++posts;
        if (t == 0)
            __hip_atomic_store(flg + gi, (unsigned)posts, __ATOMIC_RELEASE,
                               __HIP_MEMORY_SCOPE_AGENT);
        if (wv == 0) {
            for (;;) {
                unsigned v = __hip_atomic_load(flg + (ln & 15), __ATOMIC_RELAXED,
                                               __HIP_MEMORY_SCOPE_AGENT);
                if (__all((int)(v >= (unsigned)posts))) break;
                __builtin_amdgcn_s_sleep(1);
            }
            __builtin_amdgcn_fence(__ATOMIC_ACQUIRE, "agent");  // single inv, then plain loads
        }
        __syncthreads();
    };

    auto loadW = [&](const unsigned short* s0, const unsigned short* s1) {
        for (int i = t; i < N_L0 / 16 / 8; i += TPB)
            ((uint4*)Wlds)[i] = ((const uint4*)s0)[i];
        for (int i = t; i < N_L1 / 16 / 8; i += TPB)
            ((uint4*)(Wlds + WL_L1))[i] = ((const uint4*)s1)[i];
    };

    auto stageEnc = [&](const unsigned short* h0src, const unsigned short* h1src, int xs) {
        const int r = t >> 5, c8 = t & 31;
        uint4 a = *(const uint4*)(h0src + (size_t)(gb * RPG + r) * 256 + c8 * 8);
        uint4 b = *(const uint4*)(h1src + (size_t)(gb * RPG + r) * 256 + c8 * 8);
        float xv = 0.f;
        if (xs >= 0) xv = x[((size_t)(gb * RPG + r) * TIN + xs) * FF + c8];
        *(uint4*)(Atile + r * ASTRIDE + c8 * 8) = a;
        *(uint4*)(Atile + r * ASTRIDE + 256 + c8 * 8) = b;
        if (xs >= 0) Xtile[r * XSTRIDE + c8] = f2bf(xv);
    };
    auto stageOne = [&](const unsigned short* src, int colbase) {
        const int r = t >> 5, c8 = t & 31;
        uint4 a = *(const uint4*)(src + (size_t)(gb * RPG + r) * 256 + c8 * 8);
        *(uint4*)(Atile + r * ASTRIDE + colbase + c8 * 8) = a;
    };

    auto phase = [&](int wbase, int KB, bool withX, const float* bias, int layer,
                     unsigned* hdstDw) {
        const int nt = wv & 3, w2 = wv >> 2;
        const int arow = ln & 15, ak = (ln >> 4) << 3;
        const int kbs = w2 ? (KB / 2) : 0;
        const int kbe = w2 ? KB : (KB / 2);
        f32x4 acc = {0.f, 0.f, 0.f, 0.f};
        #pragma unroll
        for (int kb = kbs; kb < kbe; ++kb) {
            bf16x8 a;
            if (withX && kb == 0) a = *(const bf16x8*)(Xtile + arow * XSTRIDE + ak);
            else {
                int koff = withX ? (kb - 1) * 32 : kb * 32;
                a = *(const bf16x8*)(Atile + arow * ASTRIDE + koff + ak);
            }
            bf16x8 b = *(const bf16x8*)(Wlds + wbase + ((size_t)(nt * KB + kb) * 64 + ln) * 8);
            acc = __builtin_amdgcn_mfma_f32_16x16x32_bf16(a, b, acc, 0, 0, 0);
        }
        #pragma unroll
        for (int rg = 0; rg < 4; ++rg)        // D: col=lane&15, row=(lane>>4)*4+rg
            pbuf[w2][(ln >> 4) * 4 + rg][nt * 16 + arow] = acc[rg];
        __syncthreads();
        if (t < 128) {
            const int r = t >> 3, c2 = t & 7;
            const int c0 = c2 * 2, c1 = c0 + 1;
            float xi0 = GATE(bias, 0, r, c0), xf0 = GATE(bias, 1, r, c0);
            float xg0 = GATE(bias, 2, r, c0), xo0 = GATE(bias, 3, r, c0);
            float xi1 = GATE(bias, 0, r, c1), xf1 = GATE(bias, 1, r, c1);
            float xg1 = GATE(bias, 2, r, c1), xo1 = GATE(bias, 3, r, c1);
            float ca = cst[layer][r][c0], cb = cst[layer][r][c1];
            float cn0 = sigf(xf0) * ca + sigf(xi0) * tanhfast(xg0);
            float cn1 = sigf(xf1) * cb + sigf(xi1) * tanhfast(xg1);
            cst[layer][r][c0] = cn0; cst[layer][r][c1] = cn1;
            float h0v = sigf(xo0) * tanhfast(cn0);
            float h1v = sigf(xo1) * tanhfast(cn1);
            unsigned pv = (unsigned)f2bf(h0v) | ((unsigned)f2bf(h1v) << 16);
            __hip_atomic_store(hdstDw + (size_t)(gb * RPG + r) * 128 + gi * 8 + c2, pv,
                               __ATOMIC_RELAXED, __HIP_MEMORY_SCOPE_AGENT);
        }
        __syncthreads();
    };

    auto yphase = [&](int outTd, bool toX) {
        const int nt = wv & 1, kq = wv >> 1;
        const int arow = ln & 15, ak = (ln >> 4) << 3;
        f32x4 acc = {0.f, 0.f, 0.f, 0.f};
        #pragma unroll
        for (int i = 0; i < 2; ++i) {
            int kb = kq * 2 + i;
            bf16x8 a = *(const bf16x8*)(Atile + arow * ASTRIDE + 256 + kb * 32 + ak);
            bf16x8 b = *(const bf16x8*)(WoutLds + ((size_t)(nt * 8 + kb) * 64 + ln) * 8);
            acc = __builtin_amdgcn_mfma_f32_16x16x32_bf16(a, b, acc, 0, 0, 0);
        }
        #pragma unroll
        for (int rg = 0; rg < 4; ++rg)
            pbufY[kq][(ln >> 4) * 4 + rg][nt * 16 + arow] = acc[rg];
        __syncthreads();
        { const int r = t >> 5, f = t & 31;
          float yv = sbout[f] + pbufY[0][r][f] + pbufY[1][r][f] + pbufY[2][r][f] + pbufY[3][r][f];
          if (toX) Xtile[r * XSTRIDE + f] = f2bf(yv);
          if ((f >> 1) == gi)
              __hip_atomic_store(&out[((size_t)(gb * RPG + r) * TOUT + outTd) * FF + f], yv,
                                 __ATOMIC_RELAXED, __HIP_MEMORY_SCOPE_AGENT);
        }
        __syncthreads();
    };

    // ---- init ----
    loadW(wsu + U_E0 + (size_t)gi * (4 * KB0 * 512), wsu + U_E1 + (size_t)gi * (4 * KB1 * 512));
    { const int r = t >> 5, c8 = t & 31;
      uint4 z = {0u, 0u, 0u, 0u};
      *(uint4*)(Atile + r * ASTRIDE + c8 * 8) = z;
      Xtile[r * XSTRIDE + c8] = f2bf(x[((size_t)(gb * RPG + r) * TIN) * FF + c8]); }
    __syncthreads();

    // ---- encoder: 1 gsync/step ----
    for (int s = 0; s < TIN; ++s) {
        const int rp = s & 1, wp = rp ^ 1;
        phase(WL_L0, KB0, true, sb[0], 0, h0d + (size_t)wp * (HPAR / 2));
        gsync();                                   // publishes h0(s) (+ h1(s-1) by prior post)
        stageEnc(h0u + (size_t)wp * HPAR, h1u + (size_t)rp * HPAR,
                 (s + 1 < TIN) ? s + 1 : -1);
        __syncthreads();
        phase(WL_L1, KB1, false, sb[1], 1, h1d + (size_t)wp * (HPAR / 2));
    }

    // ---- pre-decoder ----
    loadW(wsu + U_D0 + (size_t)gi * (4 * KB0 * 512), wsu + U_D1 + (size_t)gi * (4 * KB1 * 512));
    for (int i = t; i < 8192 / 8; i += TPB)
        ((uint4*)WoutLds)[i] = ((const uint4*)(wsu + U_WOUT))[i];
    if (t < 32) sbout[t] = bout[t];
    { const int r = t >> 5, c = t & 31;            // y0 = x[:, -1, :]
      Xtile[r * XSTRIDE + c] = f2bf(x[((size_t)(gb * RPG + r) * TIN + TIN - 1) * FF + c]); }
    __syncthreads();

    // ---- decoder: 2 gsyncs/step; h0(s-1) persists in Atile cols 0..255 ----
    for (int s = TIN; s < TIN + TOUT; ++s) {
        const int rp = s & 1, wp = rp ^ 1, td = s - TIN;
        gsync();                                   // publishes h1(s-1)
        stageOne(h1u + (size_t)rp * HPAR, 256);
        __syncthreads();
        if (td > 0) yphase(td - 1, true);
        phase(WL_L0, KB0, true, sb[2], 0, h0d + (size_t)wp * (HPAR / 2));
        gsync();                                   // publishes h0(s)
        stageOne(h0u + (size_t)wp * HPAR, 0);
        __syncthreads();
        phase(WL_L1, KB1, false, sb[3], 1, h1d + (size_t)wp * (HPAR / 2));
    }

    // ---- epilogue: y(TOUT-1) from h1(431) (parity 0) ----
    gsync();
    stageOne(h1u + 0 * HPAR, 256);
    __syncthreads();
    yphase(TOUT - 1, false);
}

extern "C" void kernel_launch(void* const* d_in, const int* in_sizes, int n_in,
                              void* d_out, int out_size, void* d_ws, size_t ws_size,
                              hipStream_t stream) {
    const float* x     = (const float*)d_in[0];
    const float* eWih0 = (const float*)d_in[1];
    const float* eWhh0 = (const float*)d_in[2];
    const float* eb0   = (const float*)d_in[3];
    const float* eWih1 = (const float*)d_in[4];
    const float* eWhh1 = (const float*)d_in[5];
    const float* eb1   = (const float*)d_in[6];
    const float* dWih0 = (const float*)d_in[7];
    const float* dWhh0 = (const float*)d_in[8];
    const float* db0   = (const float*)d_in[9];
    const float* dWih1 = (const float*)d_in[10];
    const float* dWhh1 = (const float*)d_in[11];
    const float* db1   = (const float*)d_in[12];
    const float* dWout = (const float*)d_in[13];
    const float* dbout = (const float*)d_in[14];
    float* ws = (float*)d_ws;
    float* out = (float*)d_out;

    prep_kernel<<<1024, 256, 0, stream>>>(eWih0, eWhh0, eWih1, eWhh1,
                                          dWih0, dWhh0, dWih1, dWhh1, dWout, ws);
    lstm_main<<<NGS * NBG, TPB, 0, stream>>>(x, eb0, eb1, db0, db1,
                                             dWout, dbout, ws, out);
}

// Round 7
// 1985.964 us; speedup vs baseline: 5.6893x; 1.6044x over previous
//
#include <hip/hip_runtime.h>
#include <hip/hip_bf16.h>

// Problem dims
#define BB   256
#define TIN  336
#define TOUT 96
#define FF   32
#define HH   256

#define NGS 16   // gate-column slices (gi)
#define NBG 16   // batch groups (gb)
#define RPG 16   // batch rows per group
#define TPB 512

#define KB0 9        // enc L0: K=288 = [x(32) | h0(256)]
#define KB1 16       // K=512 phases
#define ASTRIDE 520  // A-tile row stride (bf16)
#define XSTRIDE 40   // X-tile row stride (bf16)

// ws layout in ushort units
#define N_L0  (16*4*KB0*64*8)      // 294912 (enc L0, K=288)
#define N_L1  (16*4*KB1*64*8)      // 524288 (K=512 regions)
#define U_E0  0
#define U_E1  (U_E0 + N_L0)        // enc L1
#define U_D0  (U_E1 + N_L1)        // dec L0' = [Whh0 | W_eff], K=512
#define U_D1  (U_D0 + N_L1)        // dec L1
#define U_END (U_D1 + N_L1)        // 1867776
#define HPAR  65536                // one parity buffer: 256x256 bf16
#define U_H0  U_END
#define U_H1  (U_H0 + 2*HPAR)
#define U_CTR (U_H1 + 2*HPAR)      // flags: [gb][32 uints]
#define U_ZEND (U_CTR + 2048)

// per-wg LDS weight slices
#define WL_E0  0
#define WL_E1  18432
#define WL_D0  0
#define WL_D1  32768
#define WL_TOT 65536               // 128 KB

#define GATE(bias, g, r, cc) (bias[(g)*16 + (cc)] + pbuf[0][r][(g)*16 + (cc)] + pbuf[1][r][(g)*16 + (cc)])

typedef __bf16 bf16x8 __attribute__((ext_vector_type(8)));
typedef float  f32x4  __attribute__((ext_vector_type(4)));

__device__ __forceinline__ float sigf(float x) { return 1.f / (1.f + __expf(-x)); }
__device__ __forceinline__ float tanhfast(float x) { return 1.f - 2.f / (__expf(2.f * x) + 1.f); }
__device__ __forceinline__ unsigned short f2bf(float f) {   // RNE bf16
    union { float f; unsigned u; } v; v.f = f;
    unsigned r = v.u + 0x7FFF + ((v.u >> 16) & 1);
    return (unsigned short)(r >> 16);
}
// coherence-point loads: bypass L1+L2 (scope-coherent), no cache-maintenance needed
__device__ __forceinline__ uint4 ldg_sc(const void* p) {
    uint4 v;
    asm volatile("global_load_dwordx4 %0, %1, off sc0 sc1\n\ts_waitcnt vmcnt(0)"
                 : "=v"(v) : "v"(p) : "memory");
    return v;
}
__device__ __forceinline__ void ldg_sc2(const void* p0, const void* p1, uint4& a, uint4& b) {
    asm volatile("global_load_dwordx4 %0, %2, off sc0 sc1\n\t"
                 "global_load_dwordx4 %1, %3, off sc0 sc1\n\t"
                 "s_waitcnt vmcnt(0)"
                 : "=v"(a), "=v"(b) : "v"(p0), "v"(p1) : "memory");
}

// ---- prep: bf16 MFMA-fragment weight slices (enc L0/L1, dec [Whh0|W_eff], dec L1); zero h/flags
__global__ void prep_kernel(const float* __restrict__ eWih0, const float* __restrict__ eWhh0,
                            const float* __restrict__ eWih1, const float* __restrict__ eWhh1,
                            const float* __restrict__ dWih0, const float* __restrict__ dWhh0,
                            const float* __restrict__ dWih1, const float* __restrict__ dWhh1,
                            const float* __restrict__ Wout,  float* __restrict__ wsf)
{
    unsigned short* wsu = (unsigned short*)wsf;
    for (long u = (long)blockIdx.x * blockDim.x + threadIdx.x; u < (long)U_END;
         u += (long)gridDim.x * blockDim.x) {
        int region; long l;
        if (u < U_E1)      { region = 0; l = u - U_E0; }
        else if (u < U_D0) { region = 1; l = u - U_E1; }
        else if (u < U_D1) { region = 2; l = u - U_D0; }
        else               { region = 3; l = u - U_D1; }
        const int KB = (region == 0) ? KB0 : KB1;
        int j = (int)(l & 7), lane = (int)((l >> 3) & 63);
        long rem = l >> 9;
        int kb = (int)(rem % KB), q = (int)(rem / KB);
        int nt = q & 3, gi = q >> 2;
        int k  = kb * 32 + ((lane >> 4) << 3) + j;
        int gj = nt * 256 + gi * 16 + (lane & 15);
        float v;
        if (region == 0)      v = (k < 32)  ? eWih0[gj * 32 + k]  : eWhh0[gj * 256 + (k - 32)];
        else if (region == 1) v = (k < 256) ? eWih1[gj * 256 + k] : eWhh1[gj * 256 + (k - 256)];
        else if (region == 2) {
            if (k < 256) v = dWhh0[gj * 256 + k];
            else {                               // W_eff[gj][k-256] = sum_f Wih0[gj][f]*Wout[f][k-256]
                float acc = 0.f; int kk = k - 256;
                #pragma unroll 8
                for (int f = 0; f < 32; ++f) acc += dWih0[gj * 32 + f] * Wout[f * 256 + kk];
                v = acc;
            }
        } else                v = (k < 256) ? dWih1[gj * 256 + k] : dWhh1[gj * 256 + (k - 256)];
        wsu[u] = f2bf(v);
    }
    for (long z = (long)blockIdx.x * blockDim.x + threadIdx.x; z < (long)(U_ZEND - U_H0);
         z += (long)gridDim.x * blockDim.x)
        wsu[U_H0 + z] = 0;
}

// ---- persistent seq2seq: 256 wgs = 16 batch-groups x 16 gate-slices, MFMA core ----
__global__ __launch_bounds__(TPB) void lstm_main(
    const float* __restrict__ x,
    const float* __restrict__ eb0, const float* __restrict__ eb1,
    const float* __restrict__ db0, const float* __restrict__ db1,
    const float* __restrict__ Wout, const float* __restrict__ bout,
    const float* __restrict__ dWih0,
    float* __restrict__ ws, float* __restrict__ out)
{
    const int gi = blockIdx.x >> 4;
    const int gb = blockIdx.x & 15;

    unsigned short* wsu = (unsigned short*)ws;
    const unsigned short* h0u = wsu + U_H0;     // consumer view (sc0sc1 loads)
    const unsigned short* h1u = wsu + U_H1;
    unsigned* h0d = (unsigned*)(wsu + U_H0);    // producer view (write-through atomic dwords)
    unsigned* h1d = (unsigned*)(wsu + U_H1);
    unsigned* flg = (unsigned*)(wsu + U_CTR) + gb * 32;

    const int t  = threadIdx.x;
    const int wv = t >> 6;
    const int ln = t & 63;

    __shared__ __align__(16) unsigned short Wlds[WL_TOT];          // 128 KB
    __shared__ __align__(16) unsigned short Atile[16 * ASTRIDE];   // 16.25 KB
    __shared__ __align__(16) unsigned short Xtile[16 * XSTRIDE];   // 1.25 KB
    __shared__ float pbuf[2][16][68];
    __shared__ float cst[2][16][16];
    __shared__ float sb[5][64];   // eb0, eb1, b_eff, db1, db0

    if (t < 64) {
        int gj = (t >> 4) * 256 + gi * 16 + (t & 15);
        sb[0][t] = eb0[gj]; sb[1][t] = eb1[gj]; sb[3][t] = db1[gj]; sb[4][t] = db0[gj];
        float be = db0[gj];
        #pragma unroll 8
        for (int f = 0; f < 32; ++f) be += dWih0[gj * 32 + f] * bout[f];
        sb[2][t] = be;
    }
    if (t < 256) { cst[0][t >> 4][t & 15] = 0.f; cst[1][t >> 4][t & 15] = 0.f; }

    int posts = 0;
    // Always entered right after a __syncthreads-terminated phase: every wave's global
    // stores are vmcnt-drained (acked at the coherence point) before the flag store below.
    auto gsync = [&]() {
        ++posts;
        if (t == 0)
            __hip_atomic_store(flg + gi, (unsigned)posts, __ATOMIC_RELAXED,
                               __HIP_MEMORY_SCOPE_AGENT);
        if (wv == 0) {
            for (;;) {
                unsigned v = __hip_atomic_load(flg + (ln & 15), __ATOMIC_RELAXED,
                                               __HIP_MEMORY_SCOPE_AGENT);
                if (__all((int)(v >= (unsigned)posts))) break;
                __builtin_amdgcn_s_sleep(1);
            }
        }
        __syncthreads();
    };

    auto loadW = [&](int d0, const unsigned short* s0, int n0,
                     int d1, const unsigned short* s1, int n1) {
        for (int i = t; i < n0; i += TPB)
            ((uint4*)(Wlds + d0))[i] = ((const uint4*)s0)[i];
        for (int i = t; i < n1; i += TPB)
            ((uint4*)(Wlds + d1))[i] = ((const uint4*)s1)[i];
    };

    auto stageEnc = [&](const unsigned short* h0src, const unsigned short* h1src, int xs) {
        const int r = t >> 5, c8 = t & 31;
        uint4 a, b;
        ldg_sc2(h0src + (size_t)(gb * RPG + r) * 256 + c8 * 8,
                h1src + (size_t)(gb * RPG + r) * 256 + c8 * 8, a, b);
        float xv = 0.f;
        if (xs >= 0) xv = x[((size_t)(gb * RPG + r) * TIN + xs) * FF + c8];
        *(uint4*)(Atile + r * ASTRIDE + c8 * 8) = a;
        *(uint4*)(Atile + r * ASTRIDE + 256 + c8 * 8) = b;
        if (xs >= 0) Xtile[r * XSTRIDE + c8] = f2bf(xv);
    };
    auto stageOne = [&](const unsigned short* src, int colbase) {
        const int r = t >> 5, c8 = t & 31;
        uint4 a = ldg_sc(src + (size_t)(gb * RPG + r) * 256 + c8 * 8);
        *(uint4*)(Atile + r * ASTRIDE + colbase + c8 * 8) = a;
    };
    auto stageTwo = [&](const unsigned short* s0, int cb0, const unsigned short* s1, int cb1) {
        const int r = t >> 5, c8 = t & 31;
        uint4 a, b;
        ldg_sc2(s0 + (size_t)(gb * RPG + r) * 256 + c8 * 8,
                s1 + (size_t)(gb * RPG + r) * 256 + c8 * 8, a, b);
        *(uint4*)(Atile + r * ASTRIDE + cb0 + c8 * 8) = a;
        *(uint4*)(Atile + r * ASTRIDE + cb1 + c8 * 8) = b;
    };
    auto stageZero = [&](int colbase) {
        const int r = t >> 5, c8 = t & 31;
        uint4 z = {0u, 0u, 0u, 0u};
        *(uint4*)(Atile + r * ASTRIDE + colbase + c8 * 8) = z;
    };

    // MFMA phase; fused cell update + write-through bf16 h store. Ends with barrier.
    auto phase = [&](int wbase, int KB, bool withX, const float* bias, int layer,
                     unsigned* hdstDw, bool addY0) {
        const int nt = wv & 3, w2 = wv >> 2;
        const int arow = ln & 15, ak = (ln >> 4) << 3;
        const int kbs = w2 ? (KB / 2) : 0;
        const int kbe = w2 ? KB : (KB / 2);
        f32x4 acc = {0.f, 0.f, 0.f, 0.f};
        #pragma unroll
        for (int kb = kbs; kb < kbe; ++kb) {
            bf16x8 a;
            if (withX && kb == 0) a = *(const bf16x8*)(Xtile + arow * XSTRIDE + ak);
            else {
                int koff = withX ? (kb - 1) * 32 : kb * 32;
                a = *(const bf16x8*)(Atile + arow * ASTRIDE + koff + ak);
            }
            bf16x8 b = *(const bf16x8*)(Wlds + wbase + ((size_t)(nt * KB + kb) * 64 + ln) * 8);
            acc = __builtin_amdgcn_mfma_f32_16x16x32_bf16(a, b, acc, 0, 0, 0);
        }
        #pragma unroll
        for (int rg = 0; rg < 4; ++rg)        // D: col=lane&15, row=(lane>>4)*4+rg
            pbuf[w2][(ln >> 4) * 4 + rg][nt * 16 + arow] = acc[rg];
        __syncthreads();
        if (t < 128) {
            const int r = t >> 3, c2 = t & 7;
            const int c0 = c2 * 2, c1 = c0 + 1;
            float xi0 = GATE(bias, 0, r, c0), xf0 = GATE(bias, 1, r, c0);
            float xg0 = GATE(bias, 2, r, c0), xo0 = GATE(bias, 3, r, c0);
            float xi1 = GATE(bias, 0, r, c1), xf1 = GATE(bias, 1, r, c1);
            float xg1 = GATE(bias, 2, r, c1), xo1 = GATE(bias, 3, r, c1);
            if (addY0) {                       // first dec step: + Wih0 * y0, y0 = x[:,-1,:]
                const float* xp = x + ((size_t)(gb * RPG + r) * TIN + (TIN - 1)) * FF;
                float xr[32];
                #pragma unroll
                for (int f = 0; f < 32; ++f) xr[f] = xp[f];
                #pragma unroll
                for (int g = 0; g < 4; ++g) {
                    const float* w0 = dWih0 + (size_t)(g * 256 + gi * 16 + c0) * 32;
                    const float* w1 = dWih0 + (size_t)(g * 256 + gi * 16 + c1) * 32;
                    float a0 = 0.f, a1 = 0.f;
                    #pragma unroll
                    for (int f = 0; f < 32; ++f) {
                        a0 = fmaf(w0[f], xr[f], a0);
                        a1 = fmaf(w1[f], xr[f], a1);
                    }
                    if (g == 0) { xi0 += a0; xi1 += a1; }
                    else if (g == 1) { xf0 += a0; xf1 += a1; }
                    else if (g == 2) { xg0 += a0; xg1 += a1; }
                    else { xo0 += a0; xo1 += a1; }
                }
            }
            float ca = cst[layer][r][c0], cb = cst[layer][r][c1];
            float cn0 = sigf(xf0) * ca + sigf(xi0) * tanhfast(xg0);
            float cn1 = sigf(xf1) * cb + sigf(xi1) * tanhfast(xg1);
            cst[layer][r][c0] = cn0; cst[layer][r][c1] = cn1;
            float h0v = sigf(xo0) * tanhfast(cn0);
            float h1v = sigf(xo1) * tanhfast(cn1);
            unsigned pv = (unsigned)f2bf(h0v) | ((unsigned)f2bf(h1v) << 16);
            __hip_atomic_store(hdstDw + (size_t)(gb * RPG + r) * 128 + gi * 8 + c2, pv,
                               __ATOMIC_RELAXED, __HIP_MEMORY_SCOPE_AGENT);
        }
        __syncthreads();
    };

    // y(outTd) from bf16 h1 in Atile cols 256..511; pure VALU, NO barriers (off critical path)
    auto computeY = [&](int outTd) {
        const int r = t >> 5, f = t & 31;
        if ((f >> 1) != gi) return;            // exactly one wg per out column pair
        const unsigned* hp = (const unsigned*)(Atile + (size_t)r * ASTRIDE + 256);
        const float* wf = Wout + (size_t)f * 256;
        float a = bout[f];
        #pragma unroll 8
        for (int q = 0; q < 128; ++q) {
            unsigned u = hp[q];
            float2 w = *(const float2*)(wf + q * 2);
            a = fmaf(__uint_as_float(u << 16), w.x, a);
            a = fmaf(__uint_as_float(u & 0xffff0000u), w.y, a);
        }
        out[((size_t)(gb * RPG + r) * TOUT + outTd) * FF + f] = a;
    };

    // ---- init: encoder weights -> LDS; h0(-1)=0; Xtile = x(0) ----
    loadW(WL_E0, wsu + U_E0 + (size_t)gi * 18432, 2304,
          WL_E1, wsu + U_E1 + (size_t)gi * 32768, 4096);
    { const int r = t >> 5, c8 = t & 31;
      uint4 z = {0u, 0u, 0u, 0u};
      *(uint4*)(Atile + r * ASTRIDE + c8 * 8) = z;
      Xtile[r * XSTRIDE + c8] = f2bf(x[((size_t)(gb * RPG + r) * TIN) * FF + c8]); }
    __syncthreads();

    // ---- encoder: 1 gsync/step ----
    for (int s = 0; s < TIN; ++s) {
        const int rp = s & 1, wp = rp ^ 1;
        phase(WL_E0, KB0, true, sb[0], 0, h0d + (size_t)wp * (HPAR / 2), false);
        gsync();                                   // publishes h0(s) (+ h1(s-1) earlier)
        stageEnc(h0u + (size_t)wp * HPAR, h1u + (size_t)rp * HPAR,
                 (s + 1 < TIN) ? s + 1 : -1);
        __syncthreads();
        phase(WL_E1, KB1, false, sb[1], 1, h1d + (size_t)wp * (HPAR / 2), false);
    }

    // ---- decoder weights -> LDS (enc phases done; gsync barrier orders before first use) ----
    loadW(WL_D0, wsu + U_D0 + (size_t)gi * 32768, 4096,
          WL_D1, wsu + U_D1 + (size_t)gi * 32768, 4096);

    // ---- decoder: 2 gsyncs/step, folded L0' = [Whh0 | W_eff]·[h0(s-1) | h1(s-1)] ----
    for (int s = TIN; s < TIN + TOUT; ++s) {
        const int rp = s & 1, wp = rp ^ 1, td = s - TIN;
        gsync();                                   // publishes h1(s-1)
        if (td == 0) stageZero(256);               // W_eff·0: y0 handled via addY0 VALU term
        else stageOne(h1u + (size_t)rp * HPAR, 256);
        __syncthreads();
        if (td > 0) computeY(td - 1);              // y(td-1) -> out (no barriers)
        phase(WL_D0, KB1, false, (td == 0) ? sb[4] : sb[2], 0,
              h0d + (size_t)wp * (HPAR / 2), td == 0);
        gsync();                                   // publishes h0(s)
        if (td == 0) stageTwo(h0u + (size_t)wp * HPAR, 0, h1u + (size_t)rp * HPAR, 256);
        else stageOne(h0u + (size_t)wp * HPAR, 0);
        __syncthreads();
        phase(WL_D1, KB1, false, sb[3], 1, h1d + (size_t)wp * (HPAR / 2), false);
    }

    // ---- epilogue: y(TOUT-1) from h1(431) (parity 0) ----
    gsync();
    stageOne(h1u + 0 * HPAR, 256);
    __syncthreads();
    computeY(TOUT - 1);
}

extern "C" void kernel_launch(void* const* d_in, const int* in_sizes, int n_in,
                              void* d_out, int out_size, void* d_ws, size_t ws_size,
                              hipStream_t stream) {
    const float* x     = (const float*)d_in[0];
    const float* eWih0 = (const float*)d_in[1];
    const float* eWhh0 = (const float*)d_in[2];
    const float* eb0   = (const float*)d_in[3];
    const float* eWih1 = (const float*)d_in[4];
    const float* eWhh1 = (const float*)d_in[5];
    const float* eb1   = (const float*)d_in[6];
    const float* dWih0 = (const float*)d_in[7];
    const float* dWhh0 = (const float*)d_in[8];
    const float* db0   = (const float*)d_in[9];
    const float* dWih1 = (const float*)d_in[10];
    const float* dWhh1 = (const float*)d_in[11];
    const float* db1   = (const float*)d_in[12];
    const float* dWout = (const float*)d_in[13];
    const float* dbout = (const float*)d_in[14];
    float* ws = (float*)d_ws;
    float* out = (float*)d_out;

    prep_kernel<<<1024, 256, 0, stream>>>(eWih0, eWhh0, eWih1, eWhh1,
                                          dWih0, dWhh0, dWih1, dWhh1, dWout, ws);
    lstm_main<<<NGS * NBG, TPB, 0, stream>>>(x, eb0, eb1, db0, db1,
                                             dWout, dbout, dWih0, ws, out);
}

// Round 8
// 1483.670 us; speedup vs baseline: 7.6154x; 1.3385x over previous
//
#include <hip/hip_runtime.h>
#include <hip/hip_bf16.h>

// Problem dims
#define BB   256
#define TIN  336
#define TOUT 96
#define FF   32
#define HH   256

#define NGS 16   // gate-column slices (gi)
#define NBG 16   // batch groups (gb)
#define RPG 16   // batch rows per group
#define TPB 512

#define KB0 9        // enc L0: K=288 = [x(32) | h0(256)]
#define KB1 16       // K=512 phases
#define ASTRIDE 520  // A-tile row stride (bf16)
#define XSTRIDE 40   // X-tile row stride (bf16)

// ws layout in ushort units
#define N_L0  (16*4*KB0*64*8)      // 294912 (enc L0, K=288)
#define N_L1  (16*4*KB1*64*8)      // 524288 (K=512 regions)
#define U_E0  0
#define U_E1  (U_E0 + N_L0)        // enc L1
#define U_D0  (U_E1 + N_L1)        // dec L0' = [Whh0 | W_eff], K=512
#define U_D1  (U_D0 + N_L1)        // dec L1
#define U_END (U_D1 + N_L1)        // 1867776
#define HPAR  65536                // one parity buffer: 256x256 bf16
#define U_H0  U_END                // h0 parity x2
#define U_H1  (U_H0 + 2*HPAR)      // h1 parity x2 (encoder)
#define U_HD  (U_H1 + 2*HPAR)      // decoder h1 per-step buffers x96
#define U_CTR (U_HD + 96*HPAR)     // flags: [gb][32 uints]
#define U_ZEND (U_CTR + 2048)

#define GATE(bias, g, r, cc) (bias[(g)*16 + (cc)] + pbuf[0][r][(g)*16 + (cc)] + pbuf[1][r][(g)*16 + (cc)])

typedef __bf16 bf16x8 __attribute__((ext_vector_type(8)));
typedef float  f32x4  __attribute__((ext_vector_type(4)));

__device__ __forceinline__ float sigf(float x) { return 1.f / (1.f + __expf(-x)); }
__device__ __forceinline__ float tanhfast(float x) { return 1.f - 2.f / (__expf(2.f * x) + 1.f); }
__device__ __forceinline__ unsigned short f2bf(float f) {   // RNE bf16
    union { float f; unsigned u; } v; v.f = f;
    unsigned r = v.u + 0x7FFF + ((v.u >> 16) & 1);
    return (unsigned short)(r >> 16);
}
// coherence-point loads (bypass L1+L2): pair with write-through producer stores
__device__ __forceinline__ uint4 ldg_sc(const void* p) {
    uint4 v;
    asm volatile("global_load_dwordx4 %0, %1, off sc0 sc1\n\ts_waitcnt vmcnt(0)"
                 : "=v"(v) : "v"(p) : "memory");
    return v;
}
__device__ __forceinline__ void ldg_sc2(const void* p0, const void* p1, uint4& a, uint4& b) {
    asm volatile("global_load_dwordx4 %0, %2, off sc0 sc1\n\t"
                 "global_load_dwordx4 %1, %3, off sc0 sc1\n\t"
                 "s_waitcnt vmcnt(0)"
                 : "=v"(a), "=v"(b) : "v"(p0), "v"(p1) : "memory");
}

// ---- prep: bf16 MFMA-fragment weight slices (enc L0/L1, dec [Whh0|W_eff], dec L1) ----
__global__ void prep_kernel(const float* __restrict__ eWih0, const float* __restrict__ eWhh0,
                            const float* __restrict__ eWih1, const float* __restrict__ eWhh1,
                            const float* __restrict__ dWih0, const float* __restrict__ dWhh0,
                            const float* __restrict__ dWih1, const float* __restrict__ dWhh1,
                            const float* __restrict__ Wout,  float* __restrict__ wsf)
{
    unsigned short* wsu = (unsigned short*)wsf;
    for (long u = (long)blockIdx.x * blockDim.x + threadIdx.x; u < (long)U_END;
         u += (long)gridDim.x * blockDim.x) {
        int region; long l;
        if (u < U_E1)      { region = 0; l = u - U_E0; }
        else if (u < U_D0) { region = 1; l = u - U_E1; }
        else if (u < U_D1) { region = 2; l = u - U_D0; }
        else               { region = 3; l = u - U_D1; }
        const int KB = (region == 0) ? KB0 : KB1;
        int j = (int)(l & 7), lane = (int)((l >> 3) & 63);
        long rem = l >> 9;
        int kb = (int)(rem % KB), q = (int)(rem / KB);
        int nt = q & 3, gi = q >> 2;
        int k  = kb * 32 + ((lane >> 4) << 3) + j;
        int gj = nt * 256 + gi * 16 + (lane & 15);
        float v;
        if (region == 0)      v = (k < 32)  ? eWih0[gj * 32 + k]  : eWhh0[gj * 256 + (k - 32)];
        else if (region == 1) v = (k < 256) ? eWih1[gj * 256 + k] : eWhh1[gj * 256 + (k - 256)];
        else if (region == 2) {
            if (k < 256) v = dWhh0[gj * 256 + k];
            else {                               // W_eff = dWih0 . Wout
                float acc = 0.f; int kk = k - 256;
                #pragma unroll 8
                for (int f = 0; f < 32; ++f) acc += dWih0[gj * 32 + f] * Wout[f * 256 + kk];
                v = acc;
            }
        } else                v = (k < 256) ? dWih1[gj * 256 + k] : dWhh1[gj * 256 + (k - 256)];
        wsu[u] = f2bf(v);
    }
    // zero parity h buffers + flags (h1dec needs no zeroing: written before read)
    for (long z = (long)blockIdx.x * blockDim.x + threadIdx.x; z < (long)(4 * HPAR);
         z += (long)gridDim.x * blockDim.x)
        wsu[U_H0 + z] = 0;
    for (long z = (long)blockIdx.x * blockDim.x + threadIdx.x; z < 2048;
         z += (long)gridDim.x * blockDim.x)
        wsu[U_CTR + z] = 0;
}

// ---- persistent seq2seq: 256 wgs = 16 batch-groups x 16 gate-slices, MFMA + reg-B ----
__global__ __launch_bounds__(TPB) void lstm_main(
    const float* __restrict__ x,
    const float* __restrict__ eb0, const float* __restrict__ eb1,
    const float* __restrict__ db0, const float* __restrict__ db1,
    const float* __restrict__ Wout, const float* __restrict__ bout,
    const float* __restrict__ dWih0,
    float* __restrict__ ws, float* __restrict__ out)
{
    const int gi = blockIdx.x >> 4;
    const int gb = blockIdx.x & 15;   // stride-16 blocks -> same XCD per group

    unsigned short* wsu = (unsigned short*)ws;
    const unsigned short* h0u = wsu + U_H0;
    const unsigned short* h1u = wsu + U_H1;
    const unsigned short* hdu = wsu + U_HD;
    unsigned* h0d = (unsigned*)(wsu + U_H0);
    unsigned* hdd = (unsigned*)(wsu + U_HD);
    unsigned* flg = (unsigned*)(wsu + U_CTR) + gb * 32;

    const int t  = threadIdx.x;
    const int wv = t >> 6;
    const int ln = t & 63;
    const int nt = wv & 3, w2 = wv >> 2;
    const int arow = ln & 15, ak = (ln >> 4) << 3;

    __shared__ __align__(16) unsigned short Atile[16 * ASTRIDE];   // 16.25 KB
    __shared__ __align__(16) unsigned short Xtile[16 * XSTRIDE];   // 1.25 KB
    __shared__ float pbuf[2][16][68];
    __shared__ float cst[2][16][16];
    __shared__ float sb[5][64];   // eb0, eb1, b_eff, db1, db0

    if (t < 64) {
        int gj = (t >> 4) * 256 + gi * 16 + (t & 15);
        sb[0][t] = eb0[gj]; sb[1][t] = eb1[gj]; sb[3][t] = db1[gj]; sb[4][t] = db0[gj];
        float be = db0[gj];
        #pragma unroll 8
        for (int f = 0; f < 32; ++f) be += dWih0[gj * 32 + f] * bout[f];
        sb[2][t] = be;
    }
    if (t < 256) { cst[0][t >> 4][t & 15] = 0.f; cst[1][t >> 4][t & 15] = 0.f; }

    // per-wave register-resident B fragments (loop-invariant per segment)
    bf16x8 B0[8], B1[8];
    const int kbs0 = w2 ? 4 : 0, kbn0 = w2 ? 5 : 4;   // enc L0 split of KB0=9
    const int kbs1 = w2 ? 8 : 0;                       // K=512 split: 8 each
    auto loadB = [&](size_t ubase, int KB, int kbs, int kbn, bf16x8* Breg) {
        #pragma unroll
        for (int i = 0; i < 8; ++i)
            if (i < kbn)
                Breg[i] = *(const bf16x8*)(wsu + ubase +
                            ((size_t)(nt * KB + kbs + i) * 64 + ln) * 8);
    };

    int posts = 0;
    // Always entered right after a __syncthreads-terminated phase: all waves' global
    // stores are vmcnt-drained (write-through, acked at IC) before the flag store.
    auto gsync = [&]() {
        ++posts;
        if (t == 0)
            __hip_atomic_store(flg + gi, (unsigned)posts, __ATOMIC_RELAXED,
                               __HIP_MEMORY_SCOPE_AGENT);
        if (wv == 0) {
            for (;;) {
                unsigned v = __hip_atomic_load(flg + (ln & 15), __ATOMIC_RELAXED,
                                               __HIP_MEMORY_SCOPE_AGENT);
                if (__all((int)(v >= (unsigned)posts))) break;
                __builtin_amdgcn_s_sleep(1);
            }
        }
        __syncthreads();
    };

    auto stageEnc = [&](const unsigned short* h0src, const unsigned short* h1src, int xs) {
        const int r = t >> 5, c8 = t & 31;
        uint4 a, b;
        ldg_sc2(h0src + (size_t)(gb * RPG + r) * 256 + c8 * 8,
                h1src + (size_t)(gb * RPG + r) * 256 + c8 * 8, a, b);
        float xv = 0.f;
        if (xs >= 0) xv = x[((size_t)(gb * RPG + r) * TIN + xs) * FF + c8];
        *(uint4*)(Atile + r * ASTRIDE + c8 * 8) = a;
        *(uint4*)(Atile + r * ASTRIDE + 256 + c8 * 8) = b;
        if (xs >= 0) Xtile[r * XSTRIDE + c8] = f2bf(xv);
    };
    auto stageOne = [&](const unsigned short* src, int colbase) {
        const int r = t >> 5, c8 = t & 31;
        uint4 a = ldg_sc(src + (size_t)(gb * RPG + r) * 256 + c8 * 8);
        *(uint4*)(Atile + r * ASTRIDE + colbase + c8 * 8) = a;
    };
    auto stageTwo = [&](const unsigned short* s0, int cb0, const unsigned short* s1, int cb1) {
        const int r = t >> 5, c8 = t & 31;
        uint4 a, b;
        ldg_sc2(s0 + (size_t)(gb * RPG + r) * 256 + c8 * 8,
                s1 + (size_t)(gb * RPG + r) * 256 + c8 * 8, a, b);
        *(uint4*)(Atile + r * ASTRIDE + cb0 + c8 * 8) = a;
        *(uint4*)(Atile + r * ASTRIDE + cb1 + c8 * 8) = b;
    };
    auto stageZero = [&](int colbase) {
        const int r = t >> 5, c8 = t & 31;
        uint4 z = {0u, 0u, 0u, 0u};
        *(uint4*)(Atile + r * ASTRIDE + colbase + c8 * 8) = z;
    };

    // MFMA phase with register B; fused cell update + write-through h store; ends barriered
    auto phase = [&](const bf16x8* Breg, int kbs, int kbn, bool withX, const float* bias,
                     int layer, unsigned* hdstDw, bool addY0) {
        f32x4 acc = {0.f, 0.f, 0.f, 0.f};
        #pragma unroll
        for (int i = 0; i < 8; ++i) {
            if (i < kbn) {
                const int kb = kbs + i;
                bf16x8 a;
                if (withX && kb == 0) a = *(const bf16x8*)(Xtile + arow * XSTRIDE + ak);
                else {
                    const int koff = (withX ? (kb - 1) : kb) * 32;
                    a = *(const bf16x8*)(Atile + arow * ASTRIDE + koff + ak);
                }
                acc = __builtin_amdgcn_mfma_f32_16x16x32_bf16(a, Breg[i], acc, 0, 0, 0);
            }
        }
        #pragma unroll
        for (int rg = 0; rg < 4; ++rg)        // D: col=lane&15, row=(lane>>4)*4+rg
            pbuf[w2][(ln >> 4) * 4 + rg][nt * 16 + arow] = acc[rg];
        __syncthreads();
        if (t < 128) {
            const int r = t >> 3, c2 = t & 7;
            const int c0 = c2 * 2, c1 = c0 + 1;
            float xi0 = GATE(bias, 0, r, c0), xf0 = GATE(bias, 1, r, c0);
            float xg0 = GATE(bias, 2, r, c0), xo0 = GATE(bias, 3, r, c0);
            float xi1 = GATE(bias, 0, r, c1), xf1 = GATE(bias, 1, r, c1);
            float xg1 = GATE(bias, 2, r, c1), xo1 = GATE(bias, 3, r, c1);
            if (addY0) {                       // first dec step: + Wih0 * y0, y0 = x[:,-1,:]
                const float* xp = x + ((size_t)(gb * RPG + r) * TIN + (TIN - 1)) * FF;
                float xr[32];
                #pragma unroll
                for (int f = 0; f < 32; ++f) xr[f] = xp[f];
                #pragma unroll
                for (int g = 0; g < 4; ++g) {
                    const float* w0 = dWih0 + (size_t)(g * 256 + gi * 16 + c0) * 32;
                    const float* w1 = dWih0 + (size_t)(g * 256 + gi * 16 + c1) * 32;
                    float a0 = 0.f, a1 = 0.f;
                    #pragma unroll
                    for (int f = 0; f < 32; ++f) {
                        a0 = fmaf(w0[f], xr[f], a0);
                        a1 = fmaf(w1[f], xr[f], a1);
                    }
                    if (g == 0) { xi0 += a0; xi1 += a1; }
                    else if (g == 1) { xf0 += a0; xf1 += a1; }
                    else if (g == 2) { xg0 += a0; xg1 += a1; }
                    else { xo0 += a0; xo1 += a1; }
                }
            }
            float ca = cst[layer][r][c0], cb = cst[layer][r][c1];
            float cn0 = sigf(xf0) * ca + sigf(xi0) * tanhfast(xg0);
            float cn1 = sigf(xf1) * cb + sigf(xi1) * tanhfast(xg1);
            cst[layer][r][c0] = cn0; cst[layer][r][c1] = cn1;
            float h0v = sigf(xo0) * tanhfast(cn0);
            float h1v = sigf(xo1) * tanhfast(cn1);
            unsigned pv = (unsigned)f2bf(h0v) | ((unsigned)f2bf(h1v) << 16);
            __hip_atomic_store(hdstDw + (size_t)(gb * RPG + r) * 128 + gi * 8 + c2, pv,
                               __ATOMIC_RELAXED, __HIP_MEMORY_SCOPE_AGENT);
        }
        __syncthreads();
    };

    // ---- init: enc B-fragments -> regs; h0(-1)=0; Xtile = x(0) ----
    loadB(U_E0 + (size_t)gi * 18432, KB0, kbs0, kbn0, B0);
    loadB(U_E1 + (size_t)gi * 32768, KB1, kbs1, 8,    B1);
    { const int r = t >> 5, c8 = t & 31;
      uint4 z = {0u, 0u, 0u, 0u};
      *(uint4*)(Atile + r * ASTRIDE + c8 * 8) = z;
      Xtile[r * XSTRIDE + c8] = f2bf(x[((size_t)(gb * RPG + r) * TIN) * FF + c8]); }
    __syncthreads();

    // ---- encoder: 1 gsync/step ----
    for (int s = 0; s < TIN; ++s) {
        const int rp = s & 1, wp = rp ^ 1;
        phase(B0, kbs0, kbn0, true, sb[0], 0, h0d + (size_t)wp * (HPAR / 2), false);
        gsync();                                   // publishes h0(s) (+ h1(s-1) earlier)
        stageEnc(h0u + (size_t)wp * HPAR, h1u + (size_t)rp * HPAR,
                 (s + 1 < TIN) ? s + 1 : -1);
        __syncthreads();
        phase(B1, kbs1, 8, false, sb[1], 1,
              (unsigned*)(wsu + U_H1) + (size_t)wp * (HPAR / 2), false);
    }

    // ---- decoder B-fragments -> regs (enc phases complete for this wave) ----
    loadB(U_D0 + (size_t)gi * 32768, KB1, kbs1, 8, B0);
    loadB(U_D1 + (size_t)gi * 32768, KB1, kbs1, 8, B1);

    // ---- decoder: 2 gsyncs/step; h0(s-1) persists in Atile cols 0..255 ----
    for (int s = TIN; s < TIN + TOUT; ++s) {
        const int wp = (s & 1) ^ 1, td = s - TIN;
        gsync();                                   // publishes h1(s-1)
        if (td == 0) stageZero(256);               // W_eff·0: y0 handled via addY0
        else stageOne(hdu + (size_t)(td - 1) * HPAR, 256);
        __syncthreads();
        phase(B0, kbs1, 8, false, (td == 0) ? sb[4] : sb[2], 0,
              h0d + (size_t)wp * (HPAR / 2), td == 0);
        gsync();                                   // publishes h0(s)
        if (td == 0) stageTwo(h0u + (size_t)wp * HPAR, 0, h1u + 0 * HPAR, 256);
        else stageOne(h0u + (size_t)wp * HPAR, 0);
        __syncthreads();
        phase(B1, kbs1, 8, false, sb[3], 1, hdd + (size_t)td * (HPAR / 2), false);
    }

    // ---- final sync: all h1dec published ----
    gsync();

    // ---- deferred y pass: out[r][td][f] for r in gb rows, f = 2gi+{0,1}; no barriers ----
    {
        const int r = t >> 5, fq = (t >> 4) & 1, kc = t & 15;
        const int f = gi * 2 + fq;
        const float* wf = Wout + (size_t)f * 256 + kc * 16;
        float wreg[16];
        #pragma unroll
        for (int i = 0; i < 16; ++i) wreg[i] = wf[i];
        const float bo = bout[f];
        for (int td = 0; td < TOUT; ++td) {
            const unsigned short* hp = hdu + (size_t)td * HPAR +
                                       (size_t)(gb * RPG + r) * 256 + kc * 16;
            uint4 ua = *(const uint4*)hp;
            uint4 ub = *(const uint4*)(hp + 8);
            unsigned w[8] = {ua.x, ua.y, ua.z, ua.w, ub.x, ub.y, ub.z, ub.w};
            float a = 0.f;
            #pragma unroll
            for (int j = 0; j < 8; ++j) {
                a = fmaf(__uint_as_float(w[j] << 16),        wreg[2 * j],     a);
                a = fmaf(__uint_as_float(w[j] & 0xffff0000u), wreg[2 * j + 1], a);
            }
            #pragma unroll
            for (int off = 1; off < 16; off <<= 1) a += __shfl_xor(a, off, 64);
            if (kc == 0)
                out[((size_t)(gb * RPG + r) * TOUT + td) * FF + f] = a + bo;
        }
    }
}

extern "C" void kernel_launch(void* const* d_in, const int* in_sizes, int n_in,
                              void* d_out, int out_size, void* d_ws, size_t ws_size,
                              hipStream_t stream) {
    const float* x     = (const float*)d_in[0];
    const float* eWih0 = (const float*)d_in[1];
    const float* eWhh0 = (const float*)d_in[2];
    const float* eb0   = (const float*)d_in[3];
    const float* eWih1 = (const float*)d_in[4];
    const float* eWhh1 = (const float*)d_in[5];
    const float* eb1   = (const float*)d_in[6];
    const float* dWih0 = (const float*)d_in[7];
    const float* dWhh0 = (const float*)d_in[8];
    const float* db0   = (const float*)d_in[9];
    const float* dWih1 = (const float*)d_in[10];
    const float* dWhh1 = (const float*)d_in[11];
    const float* db1   = (const float*)d_in[12];
    const float* dWout = (const float*)d_in[13];
    const float* dbout = (const float*)d_in[14];
    float* ws = (float*)d_ws;
    float* out = (float*)d_out;

    prep_kernel<<<1024, 256, 0, stream>>>(eWih0, eWhh0, eWih1, eWhh1,
                                          dWih0, dWhh0, dWih1, dWhh1, dWout, ws);
    lstm_main<<<NGS * NBG, TPB, 0, stream>>>(x, eb0, eb1, db0, db1,
                                             dWout, dbout, dWih0, ws, out);
}